// Round 6
// baseline (1155.878 us; speedup 1.0000x reference)
//
#include <hip/hip_runtime.h>
#include <cstddef>

typedef unsigned short u16;
typedef __attribute__((ext_vector_type(8))) short bf16x8;   // 8 bf16 in 4 VGPRs
typedef __attribute__((ext_vector_type(4))) float f32x4;

__device__ __forceinline__ u16 f2bf(float f) {
  union { float f; unsigned u; } x; x.f = f;
  unsigned r = x.u + 0x7fffu + ((x.u >> 16) & 1u);   // RNE; inputs are finite
  return (u16)(r >> 16);
}
__device__ __forceinline__ float bf2f(u16 h) {
  union { unsigned u; float f; } x; x.u = ((unsigned)h) << 16;
  return x.f;
}

// async global->LDS, 16 B per lane; LDS dest is wave-uniform base + lane*16
__device__ __forceinline__ void gll16(const u16* g, u16* ldsbase) {
  __builtin_amdgcn_global_load_lds(
      (const __attribute__((address_space(1))) void*)g,
      (__attribute__((address_space(3))) void*)ldsbase, 16, 0, 0);
}

// ---------------------------------------------------------------------------
__global__ __launch_bounds__(256) void f32_to_bf16(const float* __restrict__ in,
                                                   u16* __restrict__ out, size_t n) {
  size_t i = (size_t)blockIdx.x * 256 + threadIdx.x;
  if (i < n) out[i] = f2bf(in[i]);
}

// transpose f32 [R][C] -> bf16 [C][R]   (R,C multiples of 32) grid(C/32, R/32)
__global__ __launch_bounds__(256) void transpose_f32_bf16(const float* __restrict__ in,
                                                          u16* __restrict__ out,
                                                          int R, int C) {
  __shared__ float tile[32][33];
  int c0 = blockIdx.x * 32, r0 = blockIdx.y * 32;
  int tx = threadIdx.x & 31, ty = threadIdx.x >> 5;   // ty: 0..7
  #pragma unroll
  for (int i = ty; i < 32; i += 8)
    tile[i][tx] = in[(size_t)(r0 + i) * C + c0 + tx];
  __syncthreads();
  #pragma unroll
  for (int i = ty; i < 32; i += 8)
    out[(size_t)(c0 + i) * R + r0 + tx] = f2bf(tile[tx][i]);
}

// ---------------------------------------------------------------------------
// Tiled 8-wave GEMM: C[z][M][N] = A[z][M][K] @ Bt[z][N][K]^T, bf16 in, f32 acc.
// BK=64, 512 threads. R5: counted-lgkm software pipeline.
// R4 measured 5775 cyc/K-tile (FFN1) vs 2066 MFMA floor: the per-phase
// {issue reads -> lgkmcnt(0) FULL drain -> MFMA} serialized the LDS read
// drain (~1500 cyc at phase start, 128 b128 reads queued by 8 waves) with
// the MFMA window. Fix: issue NEXT-phase frag reads, then a COUNTED
// s_waitcnt lgkmcnt(N) that waits only the OLDER current-phase reads -> the
// new reads drain under this phase's MFMA cluster. Frag sets that span a
// phase boundary are parity ping-ponged (B in 256x256; X/Y/B in narrow),
// macro-unrolled x2 so all indices are compile-time. "memory" asm pins the
// loads; sched_barrier(0) on both sides protects the count. lgkm counts
// capped at 15 (4-bit field; over-wait of <=5 just-issued reads ~ 60 cyc).
// vmcnt waits all sit BEFORE the barrier that precedes their readers
// (cross-wave); staging overwrite windows re-verified per region.
// MFMA K-order per acc element unchanged -> bit-identical results.
// ---------------------------------------------------------------------------
enum { EPI_F32 = 0, EPI_BF16 = 1, EPI_BF16_SCALE = 2,
       EPI_BIAS_RELU_BF16 = 3, EPI_BIAS_F32 = 4 };
enum { MODE_FULL = 0, MODE_TRI = 1, MODE_CAUSAL_K = 2 };

// ---- fragment-read / MFMA macros (static indices) ----
#define RDX(SET, s)                                                           \
  {                                                                           \
    _Pragma("unroll")                                                         \
    for (int mf = 0; mf < 4; ++mf) {                                          \
      SET[mf][0] = *(const bf16x8*)((s) + rA + mf * 1024 + pg0);              \
      SET[mf][1] = *(const bf16x8*)((s) + rA + mf * 1024 + pg1);              \
    }                                                                         \
  }
#define RDY(SET, s)                                                           \
  {                                                                           \
    _Pragma("unroll")                                                         \
    for (int mf = 0; mf < 4; ++mf) {                                          \
      SET[mf][0] = *(const bf16x8*)((s) + rA + (mf + 4) * 1024 + pg0);        \
      SET[mf][1] = *(const bf16x8*)((s) + rA + (mf + 4) * 1024 + pg1);        \
    }                                                                         \
  }
#define RDBN(SET, s)                                                          \
  {                                                                           \
    _Pragma("unroll")                                                         \
    for (int nf = 0; nf < NF; ++nf) {                                         \
      SET[nf][0] = *(const bf16x8*)((s) + rB + nf * 1024 + pg0);              \
      SET[nf][1] = *(const bf16x8*)((s) + rB + nf * 1024 + pg1);              \
    }                                                                         \
  }
#define MMQ(MO, AF, BF)                                                       \
  {                                                                           \
    _Pragma("unroll")                                                         \
    for (int mf = 0; mf < 4; ++mf) {                                          \
      _Pragma("unroll")                                                       \
      for (int nf = 0; nf < NF; ++nf) {                                       \
        acc[mf + MO][nf] = __builtin_amdgcn_mfma_f32_16x16x32_bf16(           \
            BF[nf][0], AF[mf][0], acc[mf + MO][nf], 0, 0, 0);                 \
        acc[mf + MO][nf] = __builtin_amdgcn_mfma_f32_16x16x32_bf16(           \
            BF[nf][1], AF[mf][1], acc[mf + MO][nf], 0, 0, 0);                 \
      }                                                                       \
    }                                                                         \
  }

// ---- 256x256 K-tile (2 phases). BC = this tile's B set, BN_ = next's. ----
#define T256(kt, BC, BN_)                                                     \
  {                                                                           \
    const int bsel = (kt) & 1;                                                \
    const u16* sa  = &lA[bsel][0];                                            \
    const u16* sa1 = &lA[bsel ^ 1][0];                                        \
    const u16* sb1 = &lB[bsel ^ 1][0];                                        \
    /* phase A: MFMA Q(0,*) = X x BC; prefetch Y(kt); stage A(kt+1) */        \
    RDY(Y, sa);                                                               \
    if ((kt) + 1 < NT) stageA2(bsel ^ 1, (kt) + 1);                           \
    __builtin_amdgcn_sched_barrier(0);                                        \
    asm volatile("s_waitcnt lgkmcnt(8)" ::: "memory");                        \
    __builtin_amdgcn_sched_barrier(0);                                        \
    __builtin_amdgcn_s_setprio(1);                                            \
    MMQ(0, X, BC);                                                            \
    __builtin_amdgcn_s_setprio(0);                                            \
    if ((kt) + 1 < NT) asm volatile("s_waitcnt vmcnt(0)" ::: "memory");       \
    __builtin_amdgcn_s_barrier();                                             \
    /* phase B: MFMA Q(1,*) = Y x BC; prefetch X,B(kt+1); stage B(kt+2) */    \
    if ((kt) + 1 < NT) { RDX(X, sa1); RDBN(BN_, sb1); }                       \
    if ((kt) + 2 < NT) stageB2(bsel, (kt) + 2);                               \
    __builtin_amdgcn_sched_barrier(0);                                        \
    if ((kt) + 1 < NT) asm volatile("s_waitcnt lgkmcnt(15)" ::: "memory");    \
    else               asm volatile("s_waitcnt lgkmcnt(0)" ::: "memory");     \
    __builtin_amdgcn_sched_barrier(0);                                        \
    __builtin_amdgcn_s_setprio(1);                                            \
    MMQ(4, Y, BC);                                                            \
    __builtin_amdgcn_s_setprio(0);                                            \
    __builtin_amdgcn_s_barrier();                                             \
  }

// ---- narrow K-tile (1 phase, 3 LDS buffers). C = current sets, N = next. --
#define TNAR(kt, XC, YC, BC, XN, YN, BN_)                                     \
  {                                                                           \
    if ((kt) + 2 < NT) stage6(a2, b2, (kt) + 2);                              \
    if ((kt) + 1 < NT) { RDX(XN, a1); RDY(YN, a1); RDBN(BN_, b1); }           \
    __builtin_amdgcn_sched_barrier(0);                                        \
    if ((kt) + 1 < NT) asm volatile("s_waitcnt lgkmcnt(15)" ::: "memory");    \
    else               asm volatile("s_waitcnt lgkmcnt(0)" ::: "memory");     \
    __builtin_amdgcn_sched_barrier(0);                                        \
    __builtin_amdgcn_s_setprio(1);                                            \
    MMQ(0, XC, BC);                                                           \
    MMQ(4, YC, BC);                                                           \
    __builtin_amdgcn_s_setprio(0);                                            \
    if ((kt) + 1 < NT) asm volatile("s_waitcnt vmcnt(0)" ::: "memory");       \
    __builtin_amdgcn_s_barrier();                                             \
    u16* tp_;                                                                 \
    tp_ = a0; a0 = a1; a1 = a2; a2 = tp_;                                     \
    tp_ = b0; b0 = b1; b1 = b2; b2 = tp_;                                     \
  }

template <int EPI, int MODE, int BM, int BN>
__global__ __launch_bounds__(512) void gemm256(
    const u16* __restrict__ A, const u16* __restrict__ Bt,
    void* __restrict__ C0, const float* __restrict__ bias,
    const u16* __restrict__ A2, const u16* __restrict__ B2, int dsplit,
    int K, int lda, int ldb, int ldc,
    long long sA, long long sB, long long sC)
{
  constexpr int WM  = BM / 128;        // 1 or 2 M-wave groups
  constexpr int WN  = 8 / WM;          // 4 or 8 N-wave groups
  constexpr int CPW = BN / WN;         // cols per wave: 64 or 32
  constexpr int NF  = CPW / 16;        // 4 or 2 n-fragments
  constexpr int nBr = BN / 64;         // B regions (64 rows each)
  constexpr int nAr = BM / 64;         // A regions
  constexpr int NBUF = (BM == 256 && BN == 256) ? 2 : 3;

  __shared__ __align__(16) u16 lA[NBUF][BM * 64];
  __shared__ __align__(16) u16 lB[NBUF][BN * 64];

  // ---- block -> (z, mi, ni), XCD-compact swizzle (all grids %8==0) ----
  const unsigned gx = gridDim.x, gxy = gridDim.x * gridDim.y;
  unsigned id = blockIdx.x + gx * blockIdx.y + gxy * blockIdx.z;
  const unsigned nb = gxy * gridDim.z;
  unsigned p = id;
  if ((nb & 7u) == 0u) p = (id & 7u) * (nb >> 3) + (id >> 3);
  int z, mi, ni;
  if constexpr (MODE == MODE_TRI) {
    z = (int)(p / gxy);                 // gxy == tri blocks per batch
    int r = (int)(p % gxy);
    int m = 0;
    if constexpr (BN == 256) {
      while ((m + 1) * (m + 2) / 2 <= r) m++;
      mi = m; ni = r - m * (m + 1) / 2;
    } else {                            // BN=128: 2mi+2 col-tiles at row mi
      while ((m + 1) * (m + 2) <= r) m++;
      mi = m; ni = r - m * (m + 1);
    }
  } else {
    z = (int)(p / gxy);
    const unsigned rem = p % gxy;
    mi = (int)(rem / gx);
    ni = (int)(rem % gx);
  }
  // dual-source fusion (Q2+K2): upper ni half switches A/B and C offset
  if (dsplit && ni >= dsplit) {
    A = A2; Bt = B2;
    C0 = (void*)((u16*)C0 + (size_t)dsplit * BN);
    ni -= dsplit;
  }
  const int m0 = mi * BM, n0 = ni * BN;

  A  += (long long)z * sA;
  Bt += (long long)z * sB;

  int NT = K >> 6;
  if constexpr (MODE == MODE_CAUSAL_K) NT = (m0 + BM) >> 6;  // P==0 above diag

  const int t    = threadIdx.x;
  const int lane = t & 63;
  const int wave = t >> 6;
  const int wr   = (WM == 1) ? 0 : (wave >> 2);
  const int wc   = (WM == 1) ? wave : (wave & 3);
  const int quad = lane >> 4;
  const int lrow = lane & 15;

  // ---- staging addressing: pre-swizzled global source, linear LDS dest ----
  const int srow = lane >> 3;                    // 0..7 (== row & 7)
  const int scol = ((lane & 7) ^ srow) * 8;      // source granule for phys lane&7
  const u16* gAp = A  + (size_t)(m0 + wave * 8 + srow) * lda + scol;
  const u16* gBp = Bt + (size_t)(n0 + wave * 8 + srow) * ldb + scol;
  const size_t a64 = (size_t)64 * lda, b64 = (size_t)64 * ldb;
  const int lw = wave * 512;           // wave's write base within a 64-row region

  // ---- fragment read addressing (swizzled): phys granule = need ^ (row&7) ----
  const int pg0 = (quad ^ (lrow & 7)) * 8;       // ks=0
  const int pg1 = pg0 ^ 32;                      // ks=1
  const int rA = (wr * 128 + lrow) * 64;
  const int rB = (wc * CPW + lrow) * 64;

  f32x4 acc[8][NF];
  const f32x4 zero = {0.f, 0.f, 0.f, 0.f};
  #pragma unroll
  for (int i = 0; i < 8; i++)
    #pragma unroll
    for (int j = 0; j < NF; j++) acc[i][j] = zero;

  if constexpr (NBUF == 2) {
    // ================= 256x256 : counted-lgkm 2-phase pipeline =============
    bf16x8 X[4][2], Y[4][2];        // A frags (X dead after phase A -> reuse)
    bf16x8 BE[NF][2], BO[NF][2];    // B frags, tile-parity ping-pong

    auto stageB2 = [&](int b, int kt) {
      const int k = kt * 64;
      gll16(gBp + k,           &lB[b][lw]);
      gll16(gBp + k + b64,     &lB[b][4096 + lw]);
      gll16(gBp + k + 2 * b64, &lB[b][8192 + lw]);
      gll16(gBp + k + 3 * b64, &lB[b][12288 + lw]);
    };
    auto stageA2 = [&](int b, int kt) {
      const int k = kt * 64;
      gll16(gAp + k,           &lA[b][lw]);
      gll16(gAp + k + a64,     &lA[b][4096 + lw]);
      gll16(gAp + k + 2 * a64, &lA[b][8192 + lw]);
      gll16(gAp + k + 3 * a64, &lA[b][12288 + lw]);
    };

    stageB2(0, 0); stageA2(0, 0);
    if (NT > 1) {
      stageB2(1, 1);
      asm volatile("s_waitcnt vmcnt(4)" ::: "memory");   // tile0's 8 landed
    } else {
      asm volatile("s_waitcnt vmcnt(0)" ::: "memory");
    }
    __builtin_amdgcn_s_barrier();
    RDX(X, &lA[0][0]);              // tile0 phase-A frags (16 reads);
    RDBN(BE, &lB[0][0]);            // waited by phase A(0)'s lgkmcnt(8)

    for (int kt = 0; kt < NT; kt += 2) {
      T256(kt, BE, BO);
      if (kt + 1 < NT) T256(kt + 1, BO, BE);
    }
  } else {
    // ====== narrow (256x128 / 128x256) : counted-lgkm 1-phase, 3 buffers ===
    bf16x8 XE[4][2], YE[4][2], XO[4][2], YO[4][2];
    bf16x8 BE[NF][2], BO[NF][2];
    u16 *a0 = &lA[0][0], *a1 = &lA[1][0], *a2 = &lA[2][0];
    u16 *b0 = &lB[0][0], *b1 = &lB[1][0], *b2 = &lB[2][0];
    auto stage6 = [&](u16* ba, u16* bb, int kt) {
      const int k = kt * 64;
      #pragma unroll
      for (int s = 0; s < nBr; ++s)
        gll16(gBp + k + (size_t)s * b64, bb + s * 4096 + lw);
      #pragma unroll
      for (int s = 0; s < nAr; ++s)
        gll16(gAp + k + (size_t)s * a64, ba + s * 4096 + lw);
    };

    stage6(a0, b0, 0);
    if (NT > 1) stage6(a1, b1, 1);
    asm volatile("s_waitcnt vmcnt(0)" ::: "memory");   // tiles 0,1 landed
    __builtin_amdgcn_s_barrier();
    RDX(XE, a0); RDY(YE, a0); RDBN(BE, b0);   // tile0 frags (20 reads)

    for (int kt = 0; kt < NT; kt += 2) {
      TNAR(kt, XE, YE, BE, XO, YO, BO);
      if (kt + 1 < NT) TNAR(kt + 1, XO, YO, BO, XE, YE, BE);
    }
  }

  // ---- epilogue: swapped C/D layout -> lane holds 4 consecutive n ----
  const size_t zoff = (size_t)((long long)z * sC);
  #pragma unroll
  for (int mf = 0; mf < 8; ++mf) {
    #pragma unroll
    for (int nf = 0; nf < NF; ++nf) {
      const size_t m  = (size_t)(m0 + wr * 128 + mf * 16 + lrow);
      const size_t nc = (size_t)(n0 + wc * CPW + nf * 16 + quad * 4);
      const size_t idx = zoff + m * (size_t)ldc + nc;
      f32x4 v = acc[mf][nf];
      if constexpr (EPI == EPI_F32) {
        *(float4*)((float*)C0 + idx) = make_float4(v[0], v[1], v[2], v[3]);
      } else if constexpr (EPI == EPI_BF16) {
        ushort4 o; o.x = f2bf(v[0]); o.y = f2bf(v[1]); o.z = f2bf(v[2]); o.w = f2bf(v[3]);
        *(ushort4*)((u16*)C0 + idx) = o;
      } else if constexpr (EPI == EPI_BF16_SCALE) {
        ushort4 o;
        o.x = f2bf(v[0] * 0.03125f); o.y = f2bf(v[1] * 0.03125f);
        o.z = f2bf(v[2] * 0.03125f); o.w = f2bf(v[3] * 0.03125f);
        *(ushort4*)((u16*)C0 + idx) = o;
      } else if constexpr (EPI == EPI_BIAS_RELU_BF16) {
        const float4 bb = *(const float4*)(bias + nc);
        float y0 = v[0] + bb.x, y1 = v[1] + bb.y, y2 = v[2] + bb.z, y3 = v[3] + bb.w;
        ushort4 o;
        o.x = f2bf(y0 > 0.f ? y0 : 0.f); o.y = f2bf(y1 > 0.f ? y1 : 0.f);
        o.z = f2bf(y2 > 0.f ? y2 : 0.f); o.w = f2bf(y3 > 0.f ? y3 : 0.f);
        *(ushort4*)((u16*)C0 + idx) = o;
      } else {  // EPI_BIAS_F32
        const float4 bb = *(const float4*)(bias + nc);
        *(float4*)((float*)C0 + idx) =
            make_float4(v[0] + bb.x, v[1] + bb.y, v[2] + bb.z, v[3] + bb.w);
      }
    }
  }
}

#undef T256
#undef TNAR
#undef MMQ
#undef RDX
#undef RDY
#undef RDBN

// ---------------------------------------------------------------------------
// in-place row softmax on bf16 scores (already scaled); cols == 2048.
// Causal: skips loads past q and stores past the 256-aligned diagonal tile
// boundary (cols >= wlimit are never written by TRI nor read by clamped PV).
// ---------------------------------------------------------------------------
__global__ __launch_bounds__(256) void softmax_bf16(u16* __restrict__ SP, int causal) {
  __shared__ float red[8];
  const int row = blockIdx.x;
  const int q = row & 2047;
  u16* p = SP + (size_t)row * 2048;
  const int t = threadIdx.x;
  const int base = t * 8;
  const int limit  = causal ? (q + 1) : 2048;
  const int wlimit = causal ? (((q >> 8) + 1) << 8) : 2048;

  float v[8];
  if (base < limit) {
    uint4 raw = *(const uint4*)(p + base);
    unsigned w[4] = {raw.x, raw.y, raw.z, raw.w};
    #pragma unroll
    for (int j = 0; j < 4; j++) {
      union { unsigned u; float f; } lo, hi;
      lo.u = w[j] << 16; hi.u = w[j] & 0xffff0000u;
      v[2 * j] = lo.f; v[2 * j + 1] = hi.f;
    }
    #pragma unroll
    for (int j = 0; j < 8; j++) if (base + j >= limit) v[j] = -3.4e38f;
  } else {
    #pragma unroll
    for (int j = 0; j < 8; j++) v[j] = -3.4e38f;
  }

  float mx = v[0];
  #pragma unroll
  for (int j = 1; j < 8; j++) mx = fmaxf(mx, v[j]);
  #pragma unroll
  for (int o = 32; o > 0; o >>= 1) mx = fmaxf(mx, __shfl_down(mx, o));
  if ((t & 63) == 0) red[t >> 6] = mx;
  __syncthreads();
  mx = fmaxf(fmaxf(red[0], red[1]), fmaxf(red[2], red[3]));

  float s = 0.f;
  #pragma unroll
  for (int j = 0; j < 8; j++) { float e = __expf(v[j] - mx); v[j] = e; s += e; }
  #pragma unroll
  for (int o = 32; o > 0; o >>= 1) s += __shfl_down(s, o);
  if ((t & 63) == 0) red[4 + (t >> 6)] = s;
  __syncthreads();
  const float inv = 1.f / (red[4] + red[5] + red[6] + red[7]);

  if (base < wlimit) {
    unsigned o4[4];
    #pragma unroll
    for (int j = 0; j < 4; j++)
      o4[j] = (unsigned)f2bf(v[2 * j] * inv) | ((unsigned)f2bf(v[2 * j + 1] * inv) << 16);
    *(uint4*)(p + base) = make_uint4(o4[0], o4[1], o4[2], o4[3]);
  }
}

// ---------------------------------------------------------------------------
// LN(a + b) * g + be ; D == 1024; a bf16 (ABF=1) or f32 (ABF=0)
// ---------------------------------------------------------------------------
template <int ABF>
__global__ __launch_bounds__(256) void ln_residual(const void* __restrict__ a_,
                                                   const float* __restrict__ b,
                                                   const float* __restrict__ g,
                                                   const float* __restrict__ be,
                                                   float* __restrict__ outf,
                                                   u16* __restrict__ outb) {
  __shared__ float red[8];
  const size_t base = (size_t)blockIdx.x * 1024;
  const int t = threadIdx.x;
  const int i0 = t * 4;

  float va[4];
  if constexpr (ABF) {
    const ushort4 h = *(const ushort4*)((const u16*)a_ + base + i0);
    va[0] = bf2f(h.x); va[1] = bf2f(h.y); va[2] = bf2f(h.z); va[3] = bf2f(h.w);
  } else {
    const float4 f = *(const float4*)((const float*)a_ + base + i0);
    va[0] = f.x; va[1] = f.y; va[2] = f.z; va[3] = f.w;
  }
  const float4 vb = *(const float4*)(b + base + i0);
  float v[4] = {va[0] + vb.x, va[1] + vb.y, va[2] + vb.z, va[3] + vb.w};

  float s = v[0] + v[1] + v[2] + v[3];
  #pragma unroll
  for (int o = 32; o > 0; o >>= 1) s += __shfl_down(s, o);
  if ((t & 63) == 0) red[t >> 6] = s;
  __syncthreads();
  const float mean = (red[0] + red[1] + red[2] + red[3]) * (1.f / 1024.f);

  float qq = 0.f;
  #pragma unroll
  for (int i = 0; i < 4; i++) { float d = v[i] - mean; qq += d * d; }
  #pragma unroll
  for (int o = 32; o > 0; o >>= 1) qq += __shfl_down(qq, o);
  if ((t & 63) == 0) red[4 + (t >> 6)] = qq;
  __syncthreads();
  const float rstd = rsqrtf((red[4] + red[5] + red[6] + red[7]) * (1.f / 1024.f) + 1e-5f);

  const float4 gg = *(const float4*)(g + i0);
  const float4 bb = *(const float4*)(be + i0);
  float y0 = (v[0] - mean) * rstd * gg.x + bb.x;
  float y1 = (v[1] - mean) * rstd * gg.y + bb.y;
  float y2 = (v[2] - mean) * rstd * gg.z + bb.z;
  float y3 = (v[3] - mean) * rstd * gg.w + bb.w;
  if (outf) *(float4*)(outf + base + i0) = make_float4(y0, y1, y2, y3);
  if (outb) {
    ushort4 o4; o4.x = f2bf(y0); o4.y = f2bf(y1); o4.z = f2bf(y2); o4.w = f2bf(y3);
    *(ushort4*)(outb + base + i0) = o4;
  }
}

// ---------------------------------------------------------------------------
extern "C" void kernel_launch(void* const* d_in, const int* in_sizes, int n_in,
                              void* d_out, int out_size, void* d_ws, size_t ws_size,
                              hipStream_t stream)
{
  const float* y_in = (const float*)d_in[0];
  const float* Z_in = (const float*)d_in[1];
  const float* WQ1  = (const float*)d_in[2];
  const float* WK1  = (const float*)d_in[3];
  const float* WV1  = (const float*)d_in[4];
  const float* WQ2  = (const float*)d_in[5];
  const float* WK2  = (const float*)d_in[6];
  const float* WV2  = (const float*)d_in[7];
  const float* Wff1 = (const float*)d_in[8];
  const float* bff1 = (const float*)d_in[9];
  const float* Wff2 = (const float*)d_in[10];
  const float* bff2 = (const float*)d_in[11];
  const float* g1  = (const float*)d_in[12];
  const float* be1 = (const float*)d_in[13];
  const float* g2  = (const float*)d_in[14];
  const float* be2 = (const float*)d_in[15];
  const float* g3  = (const float*)d_in[16];
  const float* be3 = (const float*)d_in[17];
  (void)in_sizes; (void)n_in; (void)out_size;

  constexpr int Bn = 4, S = 2048, D = 1024, DF = 4096;
  constexpr long long BS = (long long)Bn * S;  // 8192 rows
  const long long SD = (long long)S * D;                 // 2M
  const long long SS = (long long)S * S;                 // 4M
  const long long SD2 = (long long)S * 2 * D;            // 4M: QKb batch stride

  char* ws = (char*)d_ws;
  size_t off = 0;
  auto alloc = [&](size_t bytes) -> char* {
    char* p = ws + off;
    off += (bytes + 255) & ~(size_t)255;
    return p;
  };

  // ---- workspace. NOTE: wq1t..wk1t must stay contiguous (merged Q|K weight
  // view for stage 1) — sizes are multiples of 256 B.
  u16* wq1t  = (u16*)alloc((size_t)D * D * 2);
  u16* wk1t  = (u16*)alloc((size_t)D * D * 2);
  u16* wv1t  = (u16*)alloc((size_t)D * D * 2);
  u16* wq2t  = (u16*)alloc((size_t)D * D * 2);
  u16* wk2t  = (u16*)alloc((size_t)D * D * 2);
  u16* wv2t  = (u16*)alloc((size_t)D * D * 2);
  u16* wff1t = (u16*)alloc((size_t)D * DF * 2);   // [4096][1024]
  u16* wff2t = (u16*)alloc((size_t)D * DF * 2);   // [1024][4096]
  u16* ybf   = (u16*)alloc((size_t)BS * D * 2);   // X1; reused as y1b after LN1
  u16* zbf   = (u16*)alloc((size_t)BS * D * 2);   // Z;  reused as y2b after LN2
  u16* QKb   = (u16*)alloc((size_t)BS * 2 * D * 2); // [8192][2048]: Q | K
  u16* Vtb   = (u16*)alloc((size_t)D * BS * 2);   // [1024][8192]: V^T, batch = col window
  u16* SPb   = (u16*)alloc((size_t)Bn * S * S * 2); // scores/probs bf16, in-place
  float* attnF = (float*)alloc((size_t)BS * D * 4); // attn out f32; reused as F
  u16*   y1b = ybf;
  u16*   y2b = zbf;
  u16*   Hb  = QKb;      // stage-3 hidden [8192][4096] overlays QKb|Vtb|SPb (dead)
  float* Fb  = attnF;

  if (off > ws_size) return;   // fail cleanly (absmax) instead of GPU fault

  const dim3 blk(256);
  const dim3 blk512(512);

  // ---- input converts + weight transposes ----
  f32_to_bf16<<<dim3((unsigned)((BS * D) / 256)), blk, 0, stream>>>(y_in, ybf, (size_t)BS * D);
  f32_to_bf16<<<dim3((unsigned)((BS * D) / 256)), blk, 0, stream>>>(Z_in, zbf, (size_t)BS * D);
  transpose_f32_bf16<<<dim3(D / 32, D / 32), blk, 0, stream>>>(WQ1, wq1t, D, D);
  transpose_f32_bf16<<<dim3(D / 32, D / 32), blk, 0, stream>>>(WK1, wk1t, D, D);
  transpose_f32_bf16<<<dim3(D / 32, D / 32), blk, 0, stream>>>(WV1, wv1t, D, D);
  transpose_f32_bf16<<<dim3(D / 32, D / 32), blk, 0, stream>>>(WQ2, wq2t, D, D);
  transpose_f32_bf16<<<dim3(D / 32, D / 32), blk, 0, stream>>>(WK2, wk2t, D, D);
  transpose_f32_bf16<<<dim3(D / 32, D / 32), blk, 0, stream>>>(WV2, wv2t, D, D);
  transpose_f32_bf16<<<dim3(DF / 32, D / 32), blk, 0, stream>>>(Wff1, wff1t, D, DF);
  transpose_f32_bf16<<<dim3(D / 32, DF / 32), blk, 0, stream>>>(Wff2, wff2t, DF, D);

  // ---- stage 1: causal self-attention + add&norm ----
  // Q|K projection: merged WQ^T||WK^T view (contiguous), C = QKb [8192][2048]
  gemm256<EPI_BF16, MODE_FULL, 256, 256><<<dim3(2 * D / 256, BS / 256, 1), blk512, 0, stream>>>(
      ybf, wq1t, QKb, nullptr, nullptr, nullptr, 0, D, D, D, 2 * D, 0, 0, 0);
  // V^T: Vt[d][s] = sum_k WvT[d][k] * X[s][k]  -> C [1024][8192]
  gemm256<EPI_BF16, MODE_FULL, 128, 256><<<dim3((unsigned)(BS / 256), D / 128, 1), blk512, 0, stream>>>(
      wv1t, ybf, Vtb, nullptr, nullptr, nullptr, 0, D, D, D, (int)BS, 0, 0, 0);
  // causal scores: lower-triangle 256x128 tiles (72/batch -> 288 blocks)
  gemm256<EPI_BF16_SCALE, MODE_TRI, 256, 128><<<dim3(72, 1, Bn), blk512, 0, stream>>>(
      QKb, QKb + D, SPb, nullptr, nullptr, nullptr, 0, D, 2 * D, 2 * D, S, SD2, SD2, SS);
  softmax_bf16<<<dim3((unsigned)(Bn * S)), blk, 0, stream>>>(SPb, 1);
  // PV: K-loop clamped to diagonal (P == 0 above it)
  gemm256<EPI_F32, MODE_CAUSAL_K, 256, 128><<<dim3(D / 128, S / 256, Bn), blk512, 0, stream>>>(
      SPb, Vtb, attnF, nullptr, nullptr, nullptr, 0, S, S, (int)BS, D, SS, S, SD);
  ln_residual<0><<<dim3((unsigned)BS), blk, 0, stream>>>(y_in, attnF, g1, be1, nullptr, y1b);

  // ---- stage 2: cross-attention + add&norm ----
  // fused Q2|K2 projection: ni<8 -> Q (y1b x wq2t), ni>=8 -> K (zbf x wk2t)
  gemm256<EPI_BF16, MODE_FULL, 256, 128><<<dim3(2 * D / 128, BS / 256, 1), blk512, 0, stream>>>(
      y1b, wq2t, QKb, nullptr, zbf, wk2t, 8, D, D, D, 2 * D, 0, 0, 0);
  gemm256<EPI_BF16, MODE_FULL, 128, 256><<<dim3((unsigned)(BS / 256), D / 128, 1), blk512, 0, stream>>>(
      wv2t, zbf, Vtb, nullptr, nullptr, nullptr, 0, D, D, D, (int)BS, 0, 0, 0);
  gemm256<EPI_BF16_SCALE, MODE_FULL, 256, 256><<<dim3(S / 256, S / 256, Bn), blk512, 0, stream>>>(
      QKb, QKb + D, SPb, nullptr, nullptr, nullptr, 0, D, 2 * D, 2 * D, S, SD2, SD2, SS);
  softmax_bf16<<<dim3((unsigned)(Bn * S)), blk, 0, stream>>>(SPb, 0);
  gemm256<EPI_F32, MODE_FULL, 256, 128><<<dim3(D / 128, S / 256, Bn), blk512, 0, stream>>>(
      SPb, Vtb, attnF, nullptr, nullptr, nullptr, 0, S, S, (int)BS, D, SS, S, SD);
  ln_residual<1><<<dim3((unsigned)BS), blk, 0, stream>>>(y1b, attnF, g2, be2, nullptr, y2b);

  // ---- stage 3: FFN + add&norm ----
  gemm256<EPI_BIAS_RELU_BF16, MODE_FULL, 256, 256><<<dim3(DF / 256, BS / 256, 1), blk512, 0, stream>>>(
      y2b, wff1t, Hb, bff1, nullptr, nullptr, 0, D, D, D, DF, 0, 0, 0);
  gemm256<EPI_BIAS_F32, MODE_FULL, 256, 128><<<dim3(D / 128, BS / 256, 1), blk512, 0, stream>>>(
      Hb, wff2t, Fb, bff2, nullptr, nullptr, 0, DF, DF, DF, D, 0, 0, 0);
  ln_residual<1><<<dim3((unsigned)BS), blk, 0, stream>>>(y2b, Fb, g3, be3, (float*)d_out, nullptr);
}

// Round 7
// 720.922 us; speedup vs baseline: 1.6033x; 1.6033x over previous
//
#include <hip/hip_runtime.h>
#include <cstddef>

typedef unsigned short u16;
typedef __attribute__((ext_vector_type(8))) short bf16x8;   // 8 bf16 in 4 VGPRs
typedef __attribute__((ext_vector_type(4))) float f32x4;

__device__ __forceinline__ u16 f2bf(float f) {
  union { float f; unsigned u; } x; x.f = f;
  unsigned r = x.u + 0x7fffu + ((x.u >> 16) & 1u);   // RNE; inputs are finite
  return (u16)(r >> 16);
}
__device__ __forceinline__ float bf2f(u16 h) {
  union { unsigned u; float f; } x; x.u = ((unsigned)h) << 16;
  return x.f;
}

// async global->LDS, 16 B per lane; LDS dest is wave-uniform base + lane*16
__device__ __forceinline__ void gll16(const u16* g, u16* ldsbase) {
  __builtin_amdgcn_global_load_lds(
      (const __attribute__((address_space(1))) void*)g,
      (__attribute__((address_space(3))) void*)ldsbase, 16, 0, 0);
}

// ---------------------------------------------------------------------------
__global__ __launch_bounds__(256) void f32_to_bf16(const float* __restrict__ in,
                                                   u16* __restrict__ out, size_t n) {
  size_t i = (size_t)blockIdx.x * 256 + threadIdx.x;
  if (i < n) out[i] = f2bf(in[i]);
}

// transpose f32 [R][C] -> bf16 [C][R]   (R,C multiples of 32) grid(C/32, R/32)
__global__ __launch_bounds__(256) void transpose_f32_bf16(const float* __restrict__ in,
                                                          u16* __restrict__ out,
                                                          int R, int C) {
  __shared__ float tile[32][33];
  int c0 = blockIdx.x * 32, r0 = blockIdx.y * 32;
  int tx = threadIdx.x & 31, ty = threadIdx.x >> 5;   // ty: 0..7
  #pragma unroll
  for (int i = ty; i < 32; i += 8)
    tile[i][tx] = in[(size_t)(r0 + i) * C + c0 + tx];
  __syncthreads();
  #pragma unroll
  for (int i = ty; i < 32; i += 8)
    out[(size_t)(c0 + i) * R + r0 + tx] = f2bf(tile[tx][i]);
}

// ---------------------------------------------------------------------------
// Tiled 8-wave GEMM: C[z][M][N] = A[z][M][K] @ Bt[z][N][K]^T, bf16 in, f32 acc.
// BK=64, 512 threads. R6 = R4 structure (barrier-minimal, passed @712us) +
// intra-phase sub-cluster pipelining at ZERO extra registers.
// R4's 5775 cyc/K-tile = LDS drain (~2300 cyc: 192 wave ds_read_b128 x 12cyc)
// SERIALIZED with MFMA (~2066 cyc) by the full lgkmcnt(0) before each MFMA
// cluster. R5's fix (cross-phase frag ping-pong) spilled: frag sets + acc
// exceeded the 256 VGPR/wave cap (WRITE_SIZE 65->942 MB). R6 instead issues
// all of a phase's reads into the SAME frag regs, then consumes them in
// dependency order with COUNTED lgkm waits between sub-clusters, so later
// reads drain under earlier MFMAs:
//   256^2 phase A (reads X8,B8): column-major, col nf waits lgkmcnt(6-2nf).
//   256^2 phase B (reads Y8):    row-major,    row mf waits lgkmcnt(6-2mf).
//   narrow (reads B4,X8,Y8): 8 row sub-clusters, waits 14,12,...,0.
// Correctness does not depend on the counts: hipcc inserts its own
// dependency waits before each MFMA; manual waits only tighten, and loads
// cannot sink past the "memory" asm. sched_barrier(0) fences each boundary.
// Per-acc ks0->ks1 MFMA order unchanged -> bit-identical results. Staging,
// vmcnt discipline, barriers identical to R4.
// ---------------------------------------------------------------------------
enum { EPI_F32 = 0, EPI_BF16 = 1, EPI_BF16_SCALE = 2,
       EPI_BIAS_RELU_BF16 = 3, EPI_BIAS_F32 = 4 };
enum { MODE_FULL = 0, MODE_TRI = 1, MODE_CAUSAL_K = 2 };

// counted lgkm wait + scheduling fence
#define LGKM(n)                                                               \
  asm volatile("s_waitcnt lgkmcnt(" #n ")" ::: "memory");                     \
  __builtin_amdgcn_sched_barrier(0)

// column sub-cluster (256^2 phase A): 8 MFMAs on col nfi using X
#define MMCOL(nfi)                                                            \
  __builtin_amdgcn_s_setprio(1);                                              \
  _Pragma("unroll")                                                           \
  for (int mf = 0; mf < 4; ++mf) {                                            \
    acc[mf][nfi] = __builtin_amdgcn_mfma_f32_16x16x32_bf16(                   \
        bfr[nfi][0], X[mf][0], acc[mf][nfi], 0, 0, 0);                        \
    acc[mf][nfi] = __builtin_amdgcn_mfma_f32_16x16x32_bf16(                   \
        bfr[nfi][1], X[mf][1], acc[mf][nfi], 0, 0, 0);                        \
  }                                                                           \
  __builtin_amdgcn_s_setprio(0);                                              \
  __builtin_amdgcn_sched_barrier(0)

// row sub-cluster: NF MFMA pairs on row (mi+MO) using AF[mi]
#define MMROW(AF, mi, MO)                                                     \
  __builtin_amdgcn_s_setprio(1);                                              \
  _Pragma("unroll")                                                           \
  for (int nf = 0; nf < NF; ++nf) {                                           \
    acc[(mi) + (MO)][nf] = __builtin_amdgcn_mfma_f32_16x16x32_bf16(           \
        bfr[nf][0], AF[mi][0], acc[(mi) + (MO)][nf], 0, 0, 0);                \
    acc[(mi) + (MO)][nf] = __builtin_amdgcn_mfma_f32_16x16x32_bf16(           \
        bfr[nf][1], AF[mi][1], acc[(mi) + (MO)][nf], 0, 0, 0);                \
  }                                                                           \
  __builtin_amdgcn_s_setprio(0);                                              \
  __builtin_amdgcn_sched_barrier(0)

template <int EPI, int MODE, int BM, int BN>
__global__ __launch_bounds__(512) void gemm256(
    const u16* __restrict__ A, const u16* __restrict__ Bt,
    void* __restrict__ C0, const float* __restrict__ bias,
    const u16* __restrict__ A2, const u16* __restrict__ B2, int dsplit,
    int K, int lda, int ldb, int ldc,
    long long sA, long long sB, long long sC)
{
  constexpr int WM  = BM / 128;        // 1 or 2 M-wave groups
  constexpr int WN  = 8 / WM;          // 4 or 8 N-wave groups
  constexpr int CPW = BN / WN;         // cols per wave: 64 or 32
  constexpr int NF  = CPW / 16;        // 4 or 2 n-fragments
  constexpr int nBr = BN / 64;         // B regions (64 rows each)
  constexpr int nAr = BM / 64;         // A regions
  constexpr int NBUF = (BM == 256 && BN == 256) ? 2 : 3;

  __shared__ __align__(16) u16 lA[NBUF][BM * 64];
  __shared__ __align__(16) u16 lB[NBUF][BN * 64];

  // ---- block -> (z, mi, ni), XCD-compact swizzle (all grids %8==0) ----
  const unsigned gx = gridDim.x, gxy = gridDim.x * gridDim.y;
  unsigned id = blockIdx.x + gx * blockIdx.y + gxy * blockIdx.z;
  const unsigned nb = gxy * gridDim.z;
  unsigned p = id;
  if ((nb & 7u) == 0u) p = (id & 7u) * (nb >> 3) + (id >> 3);
  int z, mi, ni;
  if constexpr (MODE == MODE_TRI) {
    z = (int)(p / gxy);                 // gxy == tri blocks per batch
    int r = (int)(p % gxy);
    int m = 0;
    if constexpr (BN == 256) {
      while ((m + 1) * (m + 2) / 2 <= r) m++;
      mi = m; ni = r - m * (m + 1) / 2;
    } else {                            // BN=128: 2mi+2 col-tiles at row mi
      while ((m + 1) * (m + 2) <= r) m++;
      mi = m; ni = r - m * (m + 1);
    }
  } else {
    z = (int)(p / gxy);
    const unsigned rem = p % gxy;
    mi = (int)(rem / gx);
    ni = (int)(rem % gx);
  }
  // dual-source fusion (Q2+K2): upper ni half switches A/B and C offset
  if (dsplit && ni >= dsplit) {
    A = A2; Bt = B2;
    C0 = (void*)((u16*)C0 + (size_t)dsplit * BN);
    ni -= dsplit;
  }
  const int m0 = mi * BM, n0 = ni * BN;

  A  += (long long)z * sA;
  Bt += (long long)z * sB;

  int NT = K >> 6;
  if constexpr (MODE == MODE_CAUSAL_K) NT = (m0 + BM) >> 6;  // P==0 above diag

  const int t    = threadIdx.x;
  const int lane = t & 63;
  const int wave = t >> 6;
  const int wr   = (WM == 1) ? 0 : (wave >> 2);
  const int wc   = (WM == 1) ? wave : (wave & 3);
  const int quad = lane >> 4;
  const int lrow = lane & 15;

  // ---- staging addressing: pre-swizzled global source, linear LDS dest ----
  const int srow = lane >> 3;                    // 0..7 (== row & 7)
  const int scol = ((lane & 7) ^ srow) * 8;      // source granule for phys lane&7
  const u16* gAp = A  + (size_t)(m0 + wave * 8 + srow) * lda + scol;
  const u16* gBp = Bt + (size_t)(n0 + wave * 8 + srow) * ldb + scol;
  const size_t a64 = (size_t)64 * lda, b64 = (size_t)64 * ldb;
  const int lw = wave * 512;           // wave's write base within a 64-row region

  // ---- fragment read addressing (swizzled): phys granule = need ^ (row&7) ----
  const int pg0 = (quad ^ (lrow & 7)) * 8;       // ks=0
  const int pg1 = pg0 ^ 32;                      // ks=1
  const int rA = (wr * 128 + lrow) * 64;
  const int rB = (wc * CPW + lrow) * 64;

  f32x4 acc[8][NF];
  const f32x4 zero = {0.f, 0.f, 0.f, 0.f};
  #pragma unroll
  for (int i = 0; i < 8; i++)
    #pragma unroll
    for (int j = 0; j < NF; j++) acc[i][j] = zero;

  bf16x8 X[4][2];      // A rows wr*128 + 0..63
  bf16x8 Y[4][2];      // A rows wr*128 + 64..127
  bf16x8 bfr[NF][2];   // B frags

  auto rdX = [&](const u16* s) {
    #pragma unroll
    for (int mf = 0; mf < 4; ++mf) {
      X[mf][0] = *(const bf16x8*)(s + rA + mf * 1024 + pg0);
      X[mf][1] = *(const bf16x8*)(s + rA + mf * 1024 + pg1);
    }
  };
  auto rdY = [&](const u16* s) {
    #pragma unroll
    for (int mf = 0; mf < 4; ++mf) {
      Y[mf][0] = *(const bf16x8*)(s + rA + (mf + 4) * 1024 + pg0);
      Y[mf][1] = *(const bf16x8*)(s + rA + (mf + 4) * 1024 + pg1);
    }
  };
  auto rdB = [&](const u16* s) {
    #pragma unroll
    for (int nf = 0; nf < NF; ++nf) {
      bfr[nf][0] = *(const bf16x8*)(s + rB + nf * 1024 + pg0);
      bfr[nf][1] = *(const bf16x8*)(s + rB + nf * 1024 + pg1);
    }
  };

  if constexpr (NBUF == 2) {
    // ===== 256x256 : 2 phases / K-tile, 1 barrier each, pipelined reads ====
    auto stageB2 = [&](int b, int kt) {
      const int k = kt * 64;
      gll16(gBp + k,           &lB[b][lw]);
      gll16(gBp + k + b64,     &lB[b][4096 + lw]);
      gll16(gBp + k + 2 * b64, &lB[b][8192 + lw]);
      gll16(gBp + k + 3 * b64, &lB[b][12288 + lw]);
    };
    auto stageA2 = [&](int b, int kt) {
      const int k = kt * 64;
      gll16(gAp + k,           &lA[b][lw]);
      gll16(gAp + k + a64,     &lA[b][4096 + lw]);
      gll16(gAp + k + 2 * a64, &lA[b][8192 + lw]);
      gll16(gAp + k + 3 * a64, &lA[b][12288 + lw]);
    };

    stageB2(0, 0); stageA2(0, 0);
    if (NT > 1) {
      stageB2(1, 1);
      asm volatile("s_waitcnt vmcnt(4)" ::: "memory");   // tile0's 8 landed
    } else {
      asm volatile("s_waitcnt vmcnt(0)" ::: "memory");
    }
    __builtin_amdgcn_s_barrier();

    for (int kt = 0; kt < NT; ++kt) {
      const int bsel = kt & 1;
      const u16* sa = &lA[bsel][0];
      const u16* sb = &lB[bsel][0];

      // ---- phase A : Q(0,*) = X x B, column-pipelined ----
      rdX(sa); rdB(sb);                             // 16 reads: X8 then B8
      if (kt + 1 < NT) stageA2(bsel ^ 1, kt + 1);   // overwrites tile kt-1 A
      LGKM(6);  MMCOL(0);                           // X + B0 landed
      LGKM(4);  MMCOL(1);
      LGKM(2);  MMCOL(2);
      LGKM(0);  MMCOL(3);
      if (kt + 1 < NT) asm volatile("s_waitcnt vmcnt(0)" ::: "memory");
      __builtin_amdgcn_s_barrier();   // A-reads done before next B-stage

      // ---- phase B : Q(1,*) = Y x B, row-pipelined ----
      rdY(sa);                                      // 8 reads
      if (kt + 2 < NT) stageB2(bsel, kt + 2);       // overwrites tile kt B
      LGKM(6);  MMROW(Y, 0, 4);
      LGKM(4);  MMROW(Y, 1, 4);
      LGKM(2);  MMROW(Y, 2, 4);
      LGKM(0);  MMROW(Y, 3, 4);
      // vmcnt(4): newest 4 = B(kt+2); A(kt+1) + older B(kt+1) retired ->
      // tile kt+1 fully in LDS for next phase A (barrier orders all waves).
      if (kt + 2 < NT)      asm volatile("s_waitcnt vmcnt(4)" ::: "memory");
      else if (kt + 1 < NT) asm volatile("s_waitcnt vmcnt(0)" ::: "memory");
      __builtin_amdgcn_s_barrier();
    }
  } else {
    // == narrow (256x128 / 128x256) : 1 phase / K-tile, 3 buffers, pipelined =
    u16 *a0 = &lA[0][0], *a1 = &lA[1][0], *a2 = &lA[2][0];
    u16 *b0 = &lB[0][0], *b1 = &lB[1][0], *b2 = &lB[2][0];
    auto stage6 = [&](u16* ba, u16* bb, int kt) {
      const int k = kt * 64;
      #pragma unroll
      for (int s = 0; s < nBr; ++s)
        gll16(gBp + k + (size_t)s * b64, bb + s * 4096 + lw);
      #pragma unroll
      for (int s = 0; s < nAr; ++s)
        gll16(gAp + k + (size_t)s * a64, ba + s * 4096 + lw);
    };

    stage6(a0, b0, 0);
    if (NT > 1) {
      stage6(a1, b1, 1);
      asm volatile("s_waitcnt vmcnt(6)" ::: "memory");   // tile0's 6 landed
    } else {
      asm volatile("s_waitcnt vmcnt(0)" ::: "memory");
    }
    __builtin_amdgcn_s_barrier();

    for (int kt = 0; kt < NT; ++kt) {
      rdB(b0); rdX(a0); rdY(a0);                    // 20 reads: B4, X8, Y8
      if (kt + 2 < NT) stage6(a2, b2, kt + 2);      // a2/b2 hold tile kt-1 (dead)
      LGKM(14); MMROW(X, 0, 0);                     // B + X0 landed
      LGKM(12); MMROW(X, 1, 0);
      LGKM(10); MMROW(X, 2, 0);
      LGKM(8);  MMROW(X, 3, 0);
      LGKM(6);  MMROW(Y, 0, 4);
      LGKM(4);  MMROW(Y, 1, 4);
      LGKM(2);  MMROW(Y, 2, 4);
      LGKM(0);  MMROW(Y, 3, 4);
      // vmcnt(6): newest 6 = tile kt+2; tile kt+1 retired -> readable next phase
      if (kt + 2 < NT)      asm volatile("s_waitcnt vmcnt(6)" ::: "memory");
      else if (kt + 1 < NT) asm volatile("s_waitcnt vmcnt(0)" ::: "memory");
      __builtin_amdgcn_s_barrier();
      u16* tp;
      tp = a0; a0 = a1; a1 = a2; a2 = tp;
      tp = b0; b0 = b1; b1 = b2; b2 = tp;
    }
  }

  // ---- epilogue: swapped C/D layout -> lane holds 4 consecutive n ----
  const size_t zoff = (size_t)((long long)z * sC);
  #pragma unroll
  for (int mf = 0; mf < 8; ++mf) {
    #pragma unroll
    for (int nf = 0; nf < NF; ++nf) {
      const size_t m  = (size_t)(m0 + wr * 128 + mf * 16 + lrow);
      const size_t nc = (size_t)(n0 + wc * CPW + nf * 16 + quad * 4);
      const size_t idx = zoff + m * (size_t)ldc + nc;
      f32x4 v = acc[mf][nf];
      if constexpr (EPI == EPI_F32) {
        *(float4*)((float*)C0 + idx) = make_float4(v[0], v[1], v[2], v[3]);
      } else if constexpr (EPI == EPI_BF16) {
        ushort4 o; o.x = f2bf(v[0]); o.y = f2bf(v[1]); o.z = f2bf(v[2]); o.w = f2bf(v[3]);
        *(ushort4*)((u16*)C0 + idx) = o;
      } else if constexpr (EPI == EPI_BF16_SCALE) {
        ushort4 o;
        o.x = f2bf(v[0] * 0.03125f); o.y = f2bf(v[1] * 0.03125f);
        o.z = f2bf(v[2] * 0.03125f); o.w = f2bf(v[3] * 0.03125f);
        *(ushort4*)((u16*)C0 + idx) = o;
      } else if constexpr (EPI == EPI_BIAS_RELU_BF16) {
        const float4 bb = *(const float4*)(bias + nc);
        float y0 = v[0] + bb.x, y1 = v[1] + bb.y, y2 = v[2] + bb.z, y3 = v[3] + bb.w;
        ushort4 o;
        o.x = f2bf(y0 > 0.f ? y0 : 0.f); o.y = f2bf(y1 > 0.f ? y1 : 0.f);
        o.z = f2bf(y2 > 0.f ? y2 : 0.f); o.w = f2bf(y3 > 0.f ? y3 : 0.f);
        *(ushort4*)((u16*)C0 + idx) = o;
      } else {  // EPI_BIAS_F32
        const float4 bb = *(const float4*)(bias + nc);
        *(float4*)((float*)C0 + idx) =
            make_float4(v[0] + bb.x, v[1] + bb.y, v[2] + bb.z, v[3] + bb.w);
      }
    }
  }
}

#undef LGKM
#undef MMCOL
#undef MMROW

// ---------------------------------------------------------------------------
// in-place row softmax on bf16 scores (already scaled); cols == 2048.
// Causal: skips loads past q and stores past the 256-aligned diagonal tile
// boundary (cols >= wlimit are never written by TRI nor read by clamped PV).
// ---------------------------------------------------------------------------
__global__ __launch_bounds__(256) void softmax_bf16(u16* __restrict__ SP, int causal) {
  __shared__ float red[8];
  const int row = blockIdx.x;
  const int q = row & 2047;
  u16* p = SP + (size_t)row * 2048;
  const int t = threadIdx.x;
  const int base = t * 8;
  const int limit  = causal ? (q + 1) : 2048;
  const int wlimit = causal ? (((q >> 8) + 1) << 8) : 2048;

  float v[8];
  if (base < limit) {
    uint4 raw = *(const uint4*)(p + base);
    unsigned w[4] = {raw.x, raw.y, raw.z, raw.w};
    #pragma unroll
    for (int j = 0; j < 4; j++) {
      union { unsigned u; float f; } lo, hi;
      lo.u = w[j] << 16; hi.u = w[j] & 0xffff0000u;
      v[2 * j] = lo.f; v[2 * j + 1] = hi.f;
    }
    #pragma unroll
    for (int j = 0; j < 8; j++) if (base + j >= limit) v[j] = -3.4e38f;
  } else {
    #pragma unroll
    for (int j = 0; j < 8; j++) v[j] = -3.4e38f;
  }

  float mx = v[0];
  #pragma unroll
  for (int j = 1; j < 8; j++) mx = fmaxf(mx, v[j]);
  #pragma unroll
  for (int o = 32; o > 0; o >>= 1) mx = fmaxf(mx, __shfl_down(mx, o));
  if ((t & 63) == 0) red[t >> 6] = mx;
  __syncthreads();
  mx = fmaxf(fmaxf(red[0], red[1]), fmaxf(red[2], red[3]));

  float s = 0.f;
  #pragma unroll
  for (int j = 0; j < 8; j++) { float e = __expf(v[j] - mx); v[j] = e; s += e; }
  #pragma unroll
  for (int o = 32; o > 0; o >>= 1) s += __shfl_down(s, o);
  if ((t & 63) == 0) red[4 + (t >> 6)] = s;
  __syncthreads();
  const float inv = 1.f / (red[4] + red[5] + red[6] + red[7]);

  if (base < wlimit) {
    unsigned o4[4];
    #pragma unroll
    for (int j = 0; j < 4; j++)
      o4[j] = (unsigned)f2bf(v[2 * j] * inv) | ((unsigned)f2bf(v[2 * j + 1] * inv) << 16);
    *(uint4*)(p + base) = make_uint4(o4[0], o4[1], o4[2], o4[3]);
  }
}

// ---------------------------------------------------------------------------
// LN(a + b) * g + be ; D == 1024; a bf16 (ABF=1) or f32 (ABF=0)
// ---------------------------------------------------------------------------
template <int ABF>
__global__ __launch_bounds__(256) void ln_residual(const void* __restrict__ a_,
                                                   const float* __restrict__ b,
                                                   const float* __restrict__ g,
                                                   const float* __restrict__ be,
                                                   float* __restrict__ outf,
                                                   u16* __restrict__ outb) {
  __shared__ float red[8];
  const size_t base = (size_t)blockIdx.x * 1024;
  const int t = threadIdx.x;
  const int i0 = t * 4;

  float va[4];
  if constexpr (ABF) {
    const ushort4 h = *(const ushort4*)((const u16*)a_ + base + i0);
    va[0] = bf2f(h.x); va[1] = bf2f(h.y); va[2] = bf2f(h.z); va[3] = bf2f(h.w);
  } else {
    const float4 f = *(const float4*)((const float*)a_ + base + i0);
    va[0] = f.x; va[1] = f.y; va[2] = f.z; va[3] = f.w;
  }
  const float4 vb = *(const float4*)(b + base + i0);
  float v[4] = {va[0] + vb.x, va[1] + vb.y, va[2] + vb.z, va[3] + vb.w};

  float s = v[0] + v[1] + v[2] + v[3];
  #pragma unroll
  for (int o = 32; o > 0; o >>= 1) s += __shfl_down(s, o);
  if ((t & 63) == 0) red[t >> 6] = s;
  __syncthreads();
  const float mean = (red[0] + red[1] + red[2] + red[3]) * (1.f / 1024.f);

  float qq = 0.f;
  #pragma unroll
  for (int i = 0; i < 4; i++) { float d = v[i] - mean; qq += d * d; }
  #pragma unroll
  for (int o = 32; o > 0; o >>= 1) qq += __shfl_down(qq, o);
  if ((t & 63) == 0) red[4 + (t >> 6)] = qq;
  __syncthreads();
  const float rstd = rsqrtf((red[4] + red[5] + red[6] + red[7]) * (1.f / 1024.f) + 1e-5f);

  const float4 gg = *(const float4*)(g + i0);
  const float4 bb = *(const float4*)(be + i0);
  float y0 = (v[0] - mean) * rstd * gg.x + bb.x;
  float y1 = (v[1] - mean) * rstd * gg.y + bb.y;
  float y2 = (v[2] - mean) * rstd * gg.z + bb.z;
  float y3 = (v[3] - mean) * rstd * gg.w + bb.w;
  if (outf) *(float4*)(outf + base + i0) = make_float4(y0, y1, y2, y3);
  if (outb) {
    ushort4 o4; o4.x = f2bf(y0); o4.y = f2bf(y1); o4.z = f2bf(y2); o4.w = f2bf(y3);
    *(ushort4*)(outb + base + i0) = o4;
  }
}

// ---------------------------------------------------------------------------
extern "C" void kernel_launch(void* const* d_in, const int* in_sizes, int n_in,
                              void* d_out, int out_size, void* d_ws, size_t ws_size,
                              hipStream_t stream)
{
  const float* y_in = (const float*)d_in[0];
  const float* Z_in = (const float*)d_in[1];
  const float* WQ1  = (const float*)d_in[2];
  const float* WK1  = (const float*)d_in[3];
  const float* WV1  = (const float*)d_in[4];
  const float* WQ2  = (const float*)d_in[5];
  const float* WK2  = (const float*)d_in[6];
  const float* WV2  = (const float*)d_in[7];
  const float* Wff1 = (const float*)d_in[8];
  const float* bff1 = (const float*)d_in[9];
  const float* Wff2 = (const float*)d_in[10];
  const float* bff2 = (const float*)d_in[11];
  const float* g1  = (const float*)d_in[12];
  const float* be1 = (const float*)d_in[13];
  const float* g2  = (const float*)d_in[14];
  const float* be2 = (const float*)d_in[15];
  const float* g3  = (const float*)d_in[16];
  const float* be3 = (const float*)d_in[17];
  (void)in_sizes; (void)n_in; (void)out_size;

  constexpr int Bn = 4, S = 2048, D = 1024, DF = 4096;
  constexpr long long BS = (long long)Bn * S;  // 8192 rows
  const long long SD = (long long)S * D;                 // 2M
  const long long SS = (long long)S * S;                 // 4M
  const long long SD2 = (long long)S * 2 * D;            // 4M: QKb batch stride

  char* ws = (char*)d_ws;
  size_t off = 0;
  auto alloc = [&](size_t bytes) -> char* {
    char* p = ws + off;
    off += (bytes + 255) & ~(size_t)255;
    return p;
  };

  // ---- workspace. NOTE: wq1t..wk1t must stay contiguous (merged Q|K weight
  // view for stage 1) — sizes are multiples of 256 B.
  u16* wq1t  = (u16*)alloc((size_t)D * D * 2);
  u16* wk1t  = (u16*)alloc((size_t)D * D * 2);
  u16* wv1t  = (u16*)alloc((size_t)D * D * 2);
  u16* wq2t  = (u16*)alloc((size_t)D * D * 2);
  u16* wk2t  = (u16*)alloc((size_t)D * D * 2);
  u16* wv2t  = (u16*)alloc((size_t)D * D * 2);
  u16* wff1t = (u16*)alloc((size_t)D * DF * 2);   // [4096][1024]
  u16* wff2t = (u16*)alloc((size_t)D * DF * 2);   // [1024][4096]
  u16* ybf   = (u16*)alloc((size_t)BS * D * 2);   // X1; reused as y1b after LN1
  u16* zbf   = (u16*)alloc((size_t)BS * D * 2);   // Z;  reused as y2b after LN2
  u16* QKb   = (u16*)alloc((size_t)BS * 2 * D * 2); // [8192][2048]: Q | K
  u16* Vtb   = (u16*)alloc((size_t)D * BS * 2);   // [1024][8192]: V^T, batch = col window
  u16* SPb   = (u16*)alloc((size_t)Bn * S * S * 2); // scores/probs bf16, in-place
  float* attnF = (float*)alloc((size_t)BS * D * 4); // attn out f32; reused as F
  u16*   y1b = ybf;
  u16*   y2b = zbf;
  u16*   Hb  = QKb;      // stage-3 hidden [8192][4096] overlays QKb|Vtb|SPb (dead)
  float* Fb  = attnF;

  if (off > ws_size) return;   // fail cleanly (absmax) instead of GPU fault

  const dim3 blk(256);
  const dim3 blk512(512);

  // ---- input converts + weight transposes ----
  f32_to_bf16<<<dim3((unsigned)((BS * D) / 256)), blk, 0, stream>>>(y_in, ybf, (size_t)BS * D);
  f32_to_bf16<<<dim3((unsigned)((BS * D) / 256)), blk, 0, stream>>>(Z_in, zbf, (size_t)BS * D);
  transpose_f32_bf16<<<dim3(D / 32, D / 32), blk, 0, stream>>>(WQ1, wq1t, D, D);
  transpose_f32_bf16<<<dim3(D / 32, D / 32), blk, 0, stream>>>(WK1, wk1t, D, D);
  transpose_f32_bf16<<<dim3(D / 32, D / 32), blk, 0, stream>>>(WV1, wv1t, D, D);
  transpose_f32_bf16<<<dim3(D / 32, D / 32), blk, 0, stream>>>(WQ2, wq2t, D, D);
  transpose_f32_bf16<<<dim3(D / 32, D / 32), blk, 0, stream>>>(WK2, wk2t, D, D);
  transpose_f32_bf16<<<dim3(D / 32, D / 32), blk, 0, stream>>>(WV2, wv2t, D, D);
  transpose_f32_bf16<<<dim3(DF / 32, D / 32), blk, 0, stream>>>(Wff1, wff1t, D, DF);
  transpose_f32_bf16<<<dim3(D / 32, DF / 32), blk, 0, stream>>>(Wff2, wff2t, DF, D);

  // ---- stage 1: causal self-attention + add&norm ----
  // Q|K projection: merged WQ^T||WK^T view (contiguous), C = QKb [8192][2048]
  gemm256<EPI_BF16, MODE_FULL, 256, 256><<<dim3(2 * D / 256, BS / 256, 1), blk512, 0, stream>>>(
      ybf, wq1t, QKb, nullptr, nullptr, nullptr, 0, D, D, D, 2 * D, 0, 0, 0);
  // V^T: Vt[d][s] = sum_k WvT[d][k] * X[s][k]  -> C [1024][8192]
  gemm256<EPI_BF16, MODE_FULL, 128, 256><<<dim3((unsigned)(BS / 256), D / 128, 1), blk512, 0, stream>>>(
      wv1t, ybf, Vtb, nullptr, nullptr, nullptr, 0, D, D, D, (int)BS, 0, 0, 0);
  // causal scores: lower-triangle 256x128 tiles (72/batch -> 288 blocks)
  gemm256<EPI_BF16_SCALE, MODE_TRI, 256, 128><<<dim3(72, 1, Bn), blk512, 0, stream>>>(
      QKb, QKb + D, SPb, nullptr, nullptr, nullptr, 0, D, 2 * D, 2 * D, S, SD2, SD2, SS);
  softmax_bf16<<<dim3((unsigned)(Bn * S)), blk, 0, stream>>>(SPb, 1);
  // PV: K-loop clamped to diagonal (P == 0 above it)
  gemm256<EPI_F32, MODE_CAUSAL_K, 256, 128><<<dim3(D / 128, S / 256, Bn), blk512, 0, stream>>>(
      SPb, Vtb, attnF, nullptr, nullptr, nullptr, 0, S, S, (int)BS, D, SS, S, SD);
  ln_residual<0><<<dim3((unsigned)BS), blk, 0, stream>>>(y_in, attnF, g1, be1, nullptr, y1b);

  // ---- stage 2: cross-attention + add&norm ----
  // fused Q2|K2 projection: ni<8 -> Q (y1b x wq2t), ni>=8 -> K (zbf x wk2t)
  gemm256<EPI_BF16, MODE_FULL, 256, 128><<<dim3(2 * D / 128, BS / 256, 1), blk512, 0, stream>>>(
      y1b, wq2t, QKb, nullptr, zbf, wk2t, 8, D, D, D, 2 * D, 0, 0, 0);
  gemm256<EPI_BF16, MODE_FULL, 128, 256><<<dim3((unsigned)(BS / 256), D / 128, 1), blk512, 0, stream>>>(
      wv2t, zbf, Vtb, nullptr, nullptr, nullptr, 0, D, D, D, (int)BS, 0, 0, 0);
  gemm256<EPI_BF16_SCALE, MODE_FULL, 256, 256><<<dim3(S / 256, S / 256, Bn), blk512, 0, stream>>>(
      QKb, QKb + D, SPb, nullptr, nullptr, nullptr, 0, D, 2 * D, 2 * D, S, SD2, SD2, SS);
  softmax_bf16<<<dim3((unsigned)(Bn * S)), blk, 0, stream>>>(SPb, 0);
  gemm256<EPI_F32, MODE_FULL, 256, 128><<<dim3(D / 128, S / 256, Bn), blk512, 0, stream>>>(
      SPb, Vtb, attnF, nullptr, nullptr, nullptr, 0, S, S, (int)BS, D, SS, S, SD);
  ln_residual<1><<<dim3((unsigned)BS), blk, 0, stream>>>(y1b, attnF, g2, be2, nullptr, y2b);

  // ---- stage 3: FFN + add&norm ----
  gemm256<EPI_BIAS_RELU_BF16, MODE_FULL, 256, 256><<<dim3(DF / 256, BS / 256, 1), blk512, 0, stream>>>(
      y2b, wff1t, Hb, bff1, nullptr, nullptr, 0, D, D, D, DF, 0, 0, 0);
  gemm256<EPI_BIAS_F32, MODE_FULL, 256, 128><<<dim3(D / 128, BS / 256, 1), blk512, 0, stream>>>(
      Hb, wff2t, Fb, bff2, nullptr, nullptr, 0, DF, DF, DF, D, 0, 0, 0);
  ln_residual<1><<<dim3((unsigned)BS), blk, 0, stream>>>(y2b, Fb, g3, be3, (float*)d_out, nullptr);
}

// Round 8
// 702.941 us; speedup vs baseline: 1.6443x; 1.0256x over previous
//
#include <hip/hip_runtime.h>
#include <cstddef>

typedef unsigned short u16;
typedef __attribute__((ext_vector_type(8))) short bf16x8;   // 8 bf16 in 4 VGPRs
typedef __attribute__((ext_vector_type(4))) float f32x4;

__device__ __forceinline__ u16 f2bf(float f) {
  union { float f; unsigned u; } x; x.f = f;
  unsigned r = x.u + 0x7fffu + ((x.u >> 16) & 1u);   // RNE; inputs are finite
  return (u16)(r >> 16);
}
__device__ __forceinline__ float bf2f(u16 h) {
  union { unsigned u; float f; } x; x.u = ((unsigned)h) << 16;
  return x.f;
}

// async global->LDS, 16 B per lane; LDS dest is wave-uniform base + lane*16
__device__ __forceinline__ void gll16(const u16* g, u16* ldsbase) {
  __builtin_amdgcn_global_load_lds(
      (const __attribute__((address_space(1))) void*)g,
      (__attribute__((address_space(3))) void*)ldsbase, 16, 0, 0);
}

// ---------------------------------------------------------------------------
__global__ __launch_bounds__(256) void f32_to_bf16(const float* __restrict__ in,
                                                   u16* __restrict__ out, size_t n) {
  size_t i = (size_t)blockIdx.x * 256 + threadIdx.x;
  if (i < n) out[i] = f2bf(in[i]);
}

// transpose f32 [R][C] -> bf16 [C][R]   (R,C multiples of 32) grid(C/32, R/32)
__global__ __launch_bounds__(256) void transpose_f32_bf16(const float* __restrict__ in,
                                                          u16* __restrict__ out,
                                                          int R, int C) {
  __shared__ float tile[32][33];
  int c0 = blockIdx.x * 32, r0 = blockIdx.y * 32;
  int tx = threadIdx.x & 31, ty = threadIdx.x >> 5;   // ty: 0..7
  #pragma unroll
  for (int i = ty; i < 32; i += 8)
    tile[i][tx] = in[(size_t)(r0 + i) * C + c0 + tx];
  __syncthreads();
  #pragma unroll
  for (int i = ty; i < 32; i += 8)
    out[(size_t)(c0 + i) * R + r0 + tx] = f2bf(tile[tx][i]);
}

// batched 1024x1024 transposes: z selects source; out stride 1024*1024
__global__ __launch_bounds__(256) void transpose6_f32_bf16(
    const float* __restrict__ s0, const float* __restrict__ s1,
    const float* __restrict__ s2, const float* __restrict__ s3,
    const float* __restrict__ s4, const float* __restrict__ s5,
    u16* __restrict__ out) {
  __shared__ float tile[32][33];
  const float* srcs[6] = {s0, s1, s2, s3, s4, s5};
  const float* in = srcs[blockIdx.z];
  u16* o = out + (size_t)blockIdx.z * 1024 * 1024;
  int c0 = blockIdx.x * 32, r0 = blockIdx.y * 32;
  int tx = threadIdx.x & 31, ty = threadIdx.x >> 5;
  #pragma unroll
  for (int i = ty; i < 32; i += 8)
    tile[i][tx] = in[(size_t)(r0 + i) * 1024 + c0 + tx];
  __syncthreads();
  #pragma unroll
  for (int i = ty; i < 32; i += 8)
    o[(size_t)(c0 + i) * 1024 + r0 + tx] = f2bf(tile[tx][i]);
}

// ---------------------------------------------------------------------------
// Tiled 8-wave GEMM: C[z][M][N] = A[z][M][K] @ Bt[z][N][K]^T, bf16 in, f32 acc.
// BK=64, 512 threads.
// R7 changes:
//  256x256: FAITHFUL m201 8-phase template (the only structure with a
//   verified 62% MfmaUtil datapoint). R1/R4/R6 variants all plateau at
//   32-36%; R1 (closest to template) deviated in: wave-divergent B reads,
//   16/4/8/0 read distribution, 2 vmcnt/tile. Fixed via stage units grouped
//   by REGION FREE-TIME: A-X regions {0,2} (read ph1) / A-Y {1,3} (ph3) /
//   B01 / B23 (both read ph1-2). Stage placement: AY(t+1)@ph1, AX(t+2)@ph2,
//   B01(t+2)@ph3, B23(t+2)@ph4; single vmcnt(6)@ph4 (newest 6 = t+2's three
//   units -> tile t+1 fully landed). Reads balanced 12/4/8/0, issued
//   PRE-barrier (service overlaps barrier-arrival skew + other waves' MFMA),
//   waited by lgkmcnt(0) after the barrier. 16 MFMA (one C-quadrant) per
//   phase in order Q(X,Blo),Q(X,Bhi),Q(Y,Bhi),Q(Y,Blo). Frag regs = R4's 96.
//  narrow (256x128 / 128x256): wave tile 64x64 (WMxWN = 4x2 / 2x4) cuts
//   per-wave reads 20->16 (-20% on the read-bound path), same MFMA count.
//   Triple-buffer 1-phase schedule unchanged from R6.
// Per-acc ks0->ks1 MFMA order unchanged everywhere -> bit-identical results.
// ---------------------------------------------------------------------------
enum { EPI_F32 = 0, EPI_BF16 = 1, EPI_BF16_SCALE = 2,
       EPI_BIAS_RELU_BF16 = 3, EPI_BIAS_F32 = 4 };
enum { MODE_FULL = 0, MODE_TRI = 1, MODE_CAUSAL_K = 2 };

// counted lgkm wait + scheduling fence
#define LGKM(n)                                                               \
  asm volatile("s_waitcnt lgkmcnt(" #n ")" ::: "memory");                     \
  __builtin_amdgcn_sched_barrier(0)

// 16-MFMA quadrant: rows AF[0..3] -> acc[MO..MO+3], cols BF2[0..1] -> NO..NO+1
#define MMQ16(AF, MO, BF2, NO)                                                \
  __builtin_amdgcn_s_setprio(1);                                              \
  _Pragma("unroll")                                                           \
  for (int mf = 0; mf < 4; ++mf) {                                            \
    _Pragma("unroll")                                                         \
    for (int nf = 0; nf < 2; ++nf) {                                          \
      acc[mf + (MO)][nf + (NO)] = __builtin_amdgcn_mfma_f32_16x16x32_bf16(    \
          BF2[nf][0], AF[mf][0], acc[mf + (MO)][nf + (NO)], 0, 0, 0);         \
      acc[mf + (MO)][nf + (NO)] = __builtin_amdgcn_mfma_f32_16x16x32_bf16(    \
          BF2[nf][1], AF[mf][1], acc[mf + (MO)][nf + (NO)], 0, 0, 0);         \
    }                                                                         \
  }                                                                           \
  __builtin_amdgcn_s_setprio(0);                                              \
  __builtin_amdgcn_sched_barrier(0)

// narrow row sub-cluster: 8 MFMAs on row mi (NF=4)
#define MMROW4(mi)                                                            \
  __builtin_amdgcn_s_setprio(1);                                              \
  _Pragma("unroll")                                                           \
  for (int nf = 0; nf < 4; ++nf) {                                            \
    acc[mi][nf] = __builtin_amdgcn_mfma_f32_16x16x32_bf16(                    \
        bfr[nf][0], X[mi][0], acc[mi][nf], 0, 0, 0);                          \
    acc[mi][nf] = __builtin_amdgcn_mfma_f32_16x16x32_bf16(                    \
        bfr[nf][1], X[mi][1], acc[mi][nf], 0, 0, 0);                          \
  }                                                                           \
  __builtin_amdgcn_s_setprio(0);                                              \
  __builtin_amdgcn_sched_barrier(0)

template <int EPI, int MODE, int BM, int BN>
__global__ __launch_bounds__(512) void gemm256(
    const u16* __restrict__ A, const u16* __restrict__ Bt,
    void* __restrict__ C0, const float* __restrict__ bias,
    const u16* __restrict__ A2, const u16* __restrict__ B2, int dsplit,
    int K, int lda, int ldb, int ldc,
    long long sA, long long sB, long long sC)
{
  constexpr int NBUF = (BM == 256 && BN == 256) ? 2 : 3;
  constexpr int WTM  = (NBUF == 2) ? 128 : 64;   // wave tile rows
  constexpr int WM   = BM / WTM;                 // wave groups in M
  constexpr int WN   = 8 / WM;                   // wave groups in N (== BN/64)
  constexpr int MF   = WTM / 16;                 // 8 or 4 m-fragments
  constexpr int nBr  = BN / 64;                  // B regions (64 rows each)
  constexpr int nAr  = BM / 64;                  // A regions

  __shared__ __align__(16) u16 lA[NBUF][BM * 64];
  __shared__ __align__(16) u16 lB[NBUF][BN * 64];

  // ---- block -> (z, mi, ni), XCD-compact swizzle (all grids %8==0) ----
  const unsigned gx = gridDim.x, gxy = gridDim.x * gridDim.y;
  unsigned id = blockIdx.x + gx * blockIdx.y + gxy * blockIdx.z;
  const unsigned nb = gxy * gridDim.z;
  unsigned p = id;
  if ((nb & 7u) == 0u) p = (id & 7u) * (nb >> 3) + (id >> 3);
  int z, mi, ni;
  if constexpr (MODE == MODE_TRI) {
    z = (int)(p / gxy);                 // gxy == tri blocks per batch
    int r = (int)(p % gxy);
    int m = 0;
    if constexpr (BN == 256) {
      while ((m + 1) * (m + 2) / 2 <= r) m++;
      mi = m; ni = r - m * (m + 1) / 2;
    } else {                            // BN=128: 2mi+2 col-tiles at row mi
      while ((m + 1) * (m + 2) <= r) m++;
      mi = m; ni = r - m * (m + 1);
    }
  } else {
    z = (int)(p / gxy);
    const unsigned rem = p % gxy;
    mi = (int)(rem / gx);
    ni = (int)(rem % gx);
  }
  // dual-source fusion (Q2+K2): upper ni half switches A/B and C offset
  if (dsplit && ni >= dsplit) {
    A = A2; Bt = B2;
    C0 = (void*)((u16*)C0 + (size_t)dsplit * BN);
    ni -= dsplit;
  }
  const int m0 = mi * BM, n0 = ni * BN;

  A  += (long long)z * sA;
  Bt += (long long)z * sB;

  int NT = K >> 6;
  if constexpr (MODE == MODE_CAUSAL_K) NT = (m0 + BM) >> 6;  // P==0 above diag

  const int t    = threadIdx.x;
  const int lane = t & 63;
  const int wave = t >> 6;
  const int wr   = wave / WN;
  const int wc   = wave % WN;
  const int quad = lane >> 4;
  const int lrow = lane & 15;

  // ---- staging addressing: pre-swizzled global source, linear LDS dest ----
  const int srow = lane >> 3;                    // 0..7 (== row & 7)
  const int scol = ((lane & 7) ^ srow) * 8;      // source granule for phys lane&7
  const u16* gAp = A  + (size_t)(m0 + wave * 8 + srow) * lda + scol;
  const u16* gBp = Bt + (size_t)(n0 + wave * 8 + srow) * ldb + scol;
  const size_t a64 = (size_t)64 * lda, b64 = (size_t)64 * ldb;
  const int lw = wave * 512;           // wave's write base within a 64-row region

  // ---- fragment read addressing (swizzled): phys granule = need ^ (row&7) ----
  const int pg0 = (quad ^ (lrow & 7)) * 8;       // ks=0
  const int pg1 = pg0 ^ 32;                      // ks=1
  const int rA = (wr * WTM + lrow) * 64;
  const int rB = (wc * 64 + lrow) * 64;

  f32x4 acc[MF][4];
  const f32x4 zero = {0.f, 0.f, 0.f, 0.f};
  #pragma unroll
  for (int i = 0; i < MF; i++)
    #pragma unroll
    for (int j = 0; j < 4; j++) acc[i][j] = zero;

  if constexpr (NBUF == 2) {
    // ================= 256x256 : faithful m201 8-phase template ============
    bf16x8 X[4][2], Y[4][2];        // A rows wr*128+0..63 / +64..127
    bf16x8 blo[2][2], bhi[2][2];    // B cols wc*64 + 0..31 / 32..63

    // stage units (2 x gll16 = one 64x64 region each), grouped by free-time
    auto stAX = [&](int b, int kt) {  // A regions 0,2 (X rows; read ph1)
      const int k = kt * 64;
      gll16(gAp + k,           &lA[b][lw]);
      gll16(gAp + k + 2 * a64, &lA[b][8192 + lw]);
    };
    auto stAY = [&](int b, int kt) {  // A regions 1,3 (Y rows; read ph3)
      const int k = kt * 64;
      gll16(gAp + k + a64,     &lA[b][4096 + lw]);
      gll16(gAp + k + 3 * a64, &lA[b][12288 + lw]);
    };
    auto stB01 = [&](int b, int kt) { // B regions 0,1 (read ph1-2 by wc=0,1)
      const int k = kt * 64;
      gll16(gBp + k,           &lB[b][lw]);
      gll16(gBp + k + b64,     &lB[b][4096 + lw]);
    };
    auto stB23 = [&](int b, int kt) { // B regions 2,3 (read ph1-2 by wc=2,3)
      const int k = kt * 64;
      gll16(gBp + k + 2 * b64, &lB[b][8192 + lw]);
      gll16(gBp + k + 3 * b64, &lB[b][12288 + lw]);
    };

    auto rdX = [&](const u16* s) {
      #pragma unroll
      for (int mf = 0; mf < 4; ++mf) {
        X[mf][0] = *(const bf16x8*)(s + rA + mf * 1024 + pg0);
        X[mf][1] = *(const bf16x8*)(s + rA + mf * 1024 + pg1);
      }
    };
    auto rdY = [&](const u16* s) {
      #pragma unroll
      for (int mf = 0; mf < 4; ++mf) {
        Y[mf][0] = *(const bf16x8*)(s + rA + (mf + 4) * 1024 + pg0);
        Y[mf][1] = *(const bf16x8*)(s + rA + (mf + 4) * 1024 + pg1);
      }
    };
    auto rdBlo = [&](const u16* s) {
      #pragma unroll
      for (int nf = 0; nf < 2; ++nf) {
        blo[nf][0] = *(const bf16x8*)(s + rB + nf * 1024 + pg0);
        blo[nf][1] = *(const bf16x8*)(s + rB + nf * 1024 + pg1);
      }
    };
    auto rdBhi = [&](const u16* s) {
      #pragma unroll
      for (int nf = 0; nf < 2; ++nf) {
        bhi[nf][0] = *(const bf16x8*)(s + rB + (nf + 2) * 1024 + pg0);
        bhi[nf][1] = *(const bf16x8*)(s + rB + (nf + 2) * 1024 + pg1);
      }
    };

    // prologue: tile0 (4 units) + tile1 (3 units; AY(1) staged at ph1 of t0)
    stAX(0, 0); stB01(0, 0); stB23(0, 0); stAY(0, 0);
    if (NT > 1) {
      stAX(1, 1); stB01(1, 1); stB23(1, 1);
      asm volatile("s_waitcnt vmcnt(6)" ::: "memory");   // tile0's 8 landed
    } else {
      asm volatile("s_waitcnt vmcnt(0)" ::: "memory");
    }
    __builtin_amdgcn_s_barrier();

    for (int kt = 0; kt < NT; ++kt) {
      const int bsel = kt & 1;
      const u16* sa = &lA[bsel][0];
      const u16* sb = &lB[bsel][0];

      // -- ph1: reads X(8)+Blo(4); stage AY(kt+1)->buf^1; MFMA Q(X,Blo) --
      rdX(sa); rdBlo(sb);
      if (kt + 1 < NT) stAY(bsel ^ 1, kt + 1);
      asm volatile("s_waitcnt lgkmcnt(8)" ::: "memory");  // start drain early
      __builtin_amdgcn_s_barrier();
      LGKM(0);
      MMQ16(X, 0, blo, 0);
      __builtin_amdgcn_s_barrier();

      // -- ph2: reads Bhi(4); stage AX(kt+2)->buf; MFMA Q(X,Bhi) --
      rdBhi(sb);
      if (kt + 2 < NT) stAX(bsel, kt + 2);
      __builtin_amdgcn_s_barrier();
      LGKM(0);
      MMQ16(X, 0, bhi, 2);
      __builtin_amdgcn_s_barrier();

      // -- ph3: reads Y(8); stage B01(kt+2); MFMA Q(Y,Bhi) --
      rdY(sa);
      if (kt + 2 < NT) stB01(bsel, kt + 2);
      __builtin_amdgcn_s_barrier();
      LGKM(0);
      MMQ16(Y, 4, bhi, 2);
      __builtin_amdgcn_s_barrier();

      // -- ph4: stage B23(kt+2); vmcnt(6) -> tile kt+1 landed; MFMA Q(Y,Blo) --
      if (kt + 2 < NT) {
        stB23(bsel, kt + 2);
        asm volatile("s_waitcnt vmcnt(6)" ::: "memory");
      } else if (kt + 1 < NT) {
        asm volatile("s_waitcnt vmcnt(0)" ::: "memory");
      }
      __builtin_amdgcn_s_barrier();
      MMQ16(Y, 4, blo, 0);
      __builtin_amdgcn_s_barrier();
    }
  } else {
    // == narrow (256x128 / 128x256) : wave 64x64, 1 phase, 3 LDS buffers ====
    bf16x8 X[4][2];      // A rows wr*64 + 0..63
    bf16x8 bfr[4][2];    // B cols wc*64 + 0..63
    u16 *a0 = &lA[0][0], *a1 = &lA[1][0], *a2 = &lA[2][0];
    u16 *b0 = &lB[0][0], *b1 = &lB[1][0], *b2 = &lB[2][0];
    auto stage6 = [&](u16* ba, u16* bb, int kt) {
      const int k = kt * 64;
      #pragma unroll
      for (int s = 0; s < nBr; ++s)
        gll16(gBp + k + (size_t)s * b64, bb + s * 4096 + lw);
      #pragma unroll
      for (int s = 0; s < nAr; ++s)
        gll16(gAp + k + (size_t)s * a64, ba + s * 4096 + lw);
    };
    auto rdB4 = [&](const u16* s) {
      #pragma unroll
      for (int nf = 0; nf < 4; ++nf) {
        bfr[nf][0] = *(const bf16x8*)(s + rB + nf * 1024 + pg0);
        bfr[nf][1] = *(const bf16x8*)(s + rB + nf * 1024 + pg1);
      }
    };
    auto rdX4 = [&](const u16* s) {
      #pragma unroll
      for (int mf = 0; mf < 4; ++mf) {
        X[mf][0] = *(const bf16x8*)(s + rA + mf * 1024 + pg0);
        X[mf][1] = *(const bf16x8*)(s + rA + mf * 1024 + pg1);
      }
    };

    stage6(a0, b0, 0);
    if (NT > 1) {
      stage6(a1, b1, 1);
      asm volatile("s_waitcnt vmcnt(6)" ::: "memory");   // tile0's 6 landed
    } else {
      asm volatile("s_waitcnt vmcnt(0)" ::: "memory");
    }
    __builtin_amdgcn_s_barrier();

    for (int kt = 0; kt < NT; ++kt) {
      rdB4(b0); rdX4(a0);                           // 16 reads: B8, X8
      if (kt + 2 < NT) stage6(a2, b2, kt + 2);      // a2/b2 hold tile kt-1 (dead)
      LGKM(6);  MMROW4(0);                          // B + X0 landed
      LGKM(4);  MMROW4(1);
      LGKM(2);  MMROW4(2);
      LGKM(0);  MMROW4(3);
      // vmcnt(6): newest 6 = tile kt+2; tile kt+1 retired -> readable next phase
      if (kt + 2 < NT)      asm volatile("s_waitcnt vmcnt(6)" ::: "memory");
      else if (kt + 1 < NT) asm volatile("s_waitcnt vmcnt(0)" ::: "memory");
      __builtin_amdgcn_s_barrier();
      u16* tp;
      tp = a0; a0 = a1; a1 = a2; a2 = tp;
      tp = b0; b0 = b1; b1 = b2; b2 = tp;
    }
  }

  // ---- epilogue: swapped C/D layout -> lane holds 4 consecutive n ----
  const size_t zoff = (size_t)((long long)z * sC);
  #pragma unroll
  for (int mf = 0; mf < MF; ++mf) {
    #pragma unroll
    for (int nf = 0; nf < 4; ++nf) {
      const size_t m  = (size_t)(m0 + wr * WTM + mf * 16 + lrow);
      const size_t nc = (size_t)(n0 + wc * 64 + nf * 16 + quad * 4);
      const size_t idx = zoff + m * (size_t)ldc + nc;
      f32x4 v = acc[mf][nf];
      if constexpr (EPI == EPI_F32) {
        *(float4*)((float*)C0 + idx) = make_float4(v[0], v[1], v[2], v[3]);
      } else if constexpr (EPI == EPI_BF16) {
        ushort4 o; o.x = f2bf(v[0]); o.y = f2bf(v[1]); o.z = f2bf(v[2]); o.w = f2bf(v[3]);
        *(ushort4*)((u16*)C0 + idx) = o;
      } else if constexpr (EPI == EPI_BF16_SCALE) {
        ushort4 o;
        o.x = f2bf(v[0] * 0.03125f); o.y = f2bf(v[1] * 0.03125f);
        o.z = f2bf(v[2] * 0.03125f); o.w = f2bf(v[3] * 0.03125f);
        *(ushort4*)((u16*)C0 + idx) = o;
      } else if constexpr (EPI == EPI_BIAS_RELU_BF16) {
        const float4 bb = *(const float4*)(bias + nc);
        float y0 = v[0] + bb.x, y1 = v[1] + bb.y, y2 = v[2] + bb.z, y3 = v[3] + bb.w;
        ushort4 o;
        o.x = f2bf(y0 > 0.f ? y0 : 0.f); o.y = f2bf(y1 > 0.f ? y1 : 0.f);
        o.z = f2bf(y2 > 0.f ? y2 : 0.f); o.w = f2bf(y3 > 0.f ? y3 : 0.f);
        *(ushort4*)((u16*)C0 + idx) = o;
      } else {  // EPI_BIAS_F32
        const float4 bb = *(const float4*)(bias + nc);
        *(float4*)((float*)C0 + idx) =
            make_float4(v[0] + bb.x, v[1] + bb.y, v[2] + bb.z, v[3] + bb.w);
      }
    }
  }
}

#undef LGKM
#undef MMQ16
#undef MMROW4

// ---------------------------------------------------------------------------
// in-place row softmax on bf16 scores (already scaled); cols == 2048.
// Causal: skips loads past q and stores past the 256-aligned diagonal tile
// boundary (cols >= wlimit are never written by TRI nor read by clamped PV).
// ---------------------------------------------------------------------------
__global__ __launch_bounds__(256) void softmax_bf16(u16* __restrict__ SP, int causal) {
  __shared__ float red[8];
  const int row = blockIdx.x;
  const int q = row & 2047;
  u16* p = SP + (size_t)row * 2048;
  const int t = threadIdx.x;
  const int base = t * 8;
  const int limit  = causal ? (q + 1) : 2048;
  const int wlimit = causal ? (((q >> 8) + 1) << 8) : 2048;

  float v[8];
  if (base < limit) {
    uint4 raw = *(const uint4*)(p + base);
    unsigned w[4] = {raw.x, raw.y, raw.z, raw.w};
    #pragma unroll
    for (int j = 0; j < 4; j++) {
      union { unsigned u; float f; } lo, hi;
      lo.u = w[j] << 16; hi.u = w[j] & 0xffff0000u;
      v[2 * j] = lo.f; v[2 * j + 1] = hi.f;
    }
    #pragma unroll
    for (int j = 0; j < 8; j++) if (base + j >= limit) v[j] = -3.4e38f;
  } else {
    #pragma unroll
    for (int j = 0; j < 8; j++) v[j] = -3.4e38f;
  }

  float mx = v[0];
  #pragma unroll
  for (int j = 1; j < 8; j++) mx = fmaxf(mx, v[j]);
  #pragma unroll
  for (int o = 32; o > 0; o >>= 1) mx = fmaxf(mx, __shfl_down(mx, o));
  if ((t & 63) == 0) red[t >> 6] = mx;
  __syncthreads();
  mx = fmaxf(fmaxf(red[0], red[1]), fmaxf(red[2], red[3]));

  float s = 0.f;
  #pragma unroll
  for (int j = 0; j < 8; j++) { float e = __expf(v[j] - mx); v[j] = e; s += e; }
  #pragma unroll
  for (int o = 32; o > 0; o >>= 1) s += __shfl_down(s, o);
  if ((t & 63) == 0) red[4 + (t >> 6)] = s;
  __syncthreads();
  const float inv = 1.f / (red[4] + red[5] + red[6] + red[7]);

  if (base < wlimit) {
    unsigned o4[4];
    #pragma unroll
    for (int j = 0; j < 4; j++)
      o4[j] = (unsigned)f2bf(v[2 * j] * inv) | ((unsigned)f2bf(v[2 * j + 1] * inv) << 16);
    *(uint4*)(p + base) = make_uint4(o4[0], o4[1], o4[2], o4[3]);
  }
}

// ---------------------------------------------------------------------------
// LN(a + b) * g + be ; D == 1024; a bf16 (ABF=1) or f32 (ABF=0)
// ---------------------------------------------------------------------------
template <int ABF>
__global__ __launch_bounds__(256) void ln_residual(const void* __restrict__ a_,
                                                   const float* __restrict__ b,
                                                   const float* __restrict__ g,
                                                   const float* __restrict__ be,
                                                   float* __restrict__ outf,
                                                   u16* __restrict__ outb) {
  __shared__ float red[8];
  const size_t base = (size_t)blockIdx.x * 1024;
  const int t = threadIdx.x;
  const int i0 = t * 4;

  float va[4];
  if constexpr (ABF) {
    const ushort4 h = *(const ushort4*)((const u16*)a_ + base + i0);
    va[0] = bf2f(h.x); va[1] = bf2f(h.y); va[2] = bf2f(h.z); va[3] = bf2f(h.w);
  } else {
    const float4 f = *(const float4*)((const float*)a_ + base + i0);
    va[0] = f.x; va[1] = f.y; va[2] = f.z; va[3] = f.w;
  }
  const float4 vb = *(const float4*)(b + base + i0);
  float v[4] = {va[0] + vb.x, va[1] + vb.y, va[2] + vb.z, va[3] + vb.w};

  float s = v[0] + v[1] + v[2] + v[3];
  #pragma unroll
  for (int o = 32; o > 0; o >>= 1) s += __shfl_down(s, o);
  if ((t & 63) == 0) red[t >> 6] = s;
  __syncthreads();
  const float mean = (red[0] + red[1] + red[2] + red[3]) * (1.f / 1024.f);

  float qq = 0.f;
  #pragma unroll
  for (int i = 0; i < 4; i++) { float d = v[i] - mean; qq += d * d; }
  #pragma unroll
  for (int o = 32; o > 0; o >>= 1) qq += __shfl_down(qq, o);
  if ((t & 63) == 0) red[4 + (t >> 6)] = qq;
  __syncthreads();
  const float rstd = rsqrtf((red[4] + red[5] + red[6] + red[7]) * (1.f / 1024.f) + 1e-5f);

  const float4 gg = *(const float4*)(g + i0);
  const float4 bb = *(const float4*)(be + i0);
  float y0 = (v[0] - mean) * rstd * gg.x + bb.x;
  float y1 = (v[1] - mean) * rstd * gg.y + bb.y;
  float y2 = (v[2] - mean) * rstd * gg.z + bb.z;
  float y3 = (v[3] - mean) * rstd * gg.w + bb.w;
  if (outf) *(float4*)(outf + base + i0) = make_float4(y0, y1, y2, y3);
  if (outb) {
    ushort4 o4; o4.x = f2bf(y0); o4.y = f2bf(y1); o4.z = f2bf(y2); o4.w = f2bf(y3);
    *(ushort4*)(outb + base + i0) = o4;
  }
}

// ---------------------------------------------------------------------------
extern "C" void kernel_launch(void* const* d_in, const int* in_sizes, int n_in,
                              void* d_out, int out_size, void* d_ws, size_t ws_size,
                              hipStream_t stream)
{
  const float* y_in = (const float*)d_in[0];
  const float* Z_in = (const float*)d_in[1];
  const float* WQ1  = (const float*)d_in[2];
  const float* WK1  = (const float*)d_in[3];
  const float* WV1  = (const float*)d_in[4];
  const float* WQ2  = (const float*)d_in[5];
  const float* WK2  = (const float*)d_in[6];
  const float* WV2  = (const float*)d_in[7];
  const float* Wff1 = (const float*)d_in[8];
  const float* bff1 = (const float*)d_in[9];
  const float* Wff2 = (const float*)d_in[10];
  const float* bff2 = (const float*)d_in[11];
  const float* g1  = (const float*)d_in[12];
  const float* be1 = (const float*)d_in[13];
  const float* g2  = (const float*)d_in[14];
  const float* be2 = (const float*)d_in[15];
  const float* g3  = (const float*)d_in[16];
  const float* be3 = (const float*)d_in[17];
  (void)in_sizes; (void)n_in; (void)out_size;

  constexpr int Bn = 4, S = 2048, D = 1024, DF = 4096;
  constexpr long long BS = (long long)Bn * S;  // 8192 rows
  const long long SD = (long long)S * D;                 // 2M
  const long long SS = (long long)S * S;                 // 4M
  const long long SD2 = (long long)S * 2 * D;            // 4M: QKb batch stride

  char* ws = (char*)d_ws;
  size_t off = 0;
  auto alloc = [&](size_t bytes) -> char* {
    char* p = ws + off;
    off += (bytes + 255) & ~(size_t)255;
    return p;
  };

  // ---- workspace. NOTE: wq1t..wk1t must stay contiguous (merged Q|K weight
  // view for stage 1); wq1t..wv2t contiguous (batched transpose out) —
  // sizes are multiples of 256 B.
  u16* wq1t  = (u16*)alloc((size_t)D * D * 2);
  u16* wk1t  = (u16*)alloc((size_t)D * D * 2);
  u16* wv1t  = (u16*)alloc((size_t)D * D * 2);
  u16* wq2t  = (u16*)alloc((size_t)D * D * 2);
  u16* wk2t  = (u16*)alloc((size_t)D * D * 2);
  u16* wv2t  = (u16*)alloc((size_t)D * D * 2);
  u16* wff1t = (u16*)alloc((size_t)D * DF * 2);   // [4096][1024]
  u16* wff2t = (u16*)alloc((size_t)D * DF * 2);   // [1024][4096]
  u16* ybf   = (u16*)alloc((size_t)BS * D * 2);   // X1; reused as y1b after LN1
  u16* zbf   = (u16*)alloc((size_t)BS * D * 2);   // Z;  reused as y2b after LN2
  u16* QKb   = (u16*)alloc((size_t)BS * 2 * D * 2); // [8192][2048]: Q | K
  u16* Vtb   = (u16*)alloc((size_t)D * BS * 2);   // [1024][8192]: V^T, batch = col window
  u16* SPb   = (u16*)alloc((size_t)Bn * S * S * 2); // scores/probs bf16, in-place
  float* attnF = (float*)alloc((size_t)BS * D * 4); // attn out f32; reused as F
  u16*   y1b = ybf;
  u16*   y2b = zbf;
  u16*   Hb  = QKb;      // stage-3 hidden [8192][4096] overlays QKb|Vtb|SPb (dead)
  float* Fb  = attnF;

  if (off > ws_size) return;   // fail cleanly (absmax) instead of GPU fault

  const dim3 blk(256);
  const dim3 blk512(512);

  // ---- input converts + weight transposes ----
  f32_to_bf16<<<dim3((unsigned)((BS * D) / 256)), blk, 0, stream>>>(y_in, ybf, (size_t)BS * D);
  f32_to_bf16<<<dim3((unsigned)((BS * D) / 256)), blk, 0, stream>>>(Z_in, zbf, (size_t)BS * D);
  transpose6_f32_bf16<<<dim3(D / 32, D / 32, 6), blk, 0, stream>>>(
      WQ1, WK1, WV1, WQ2, WK2, WV2, wq1t);
  transpose_f32_bf16<<<dim3(DF / 32, D / 32), blk, 0, stream>>>(Wff1, wff1t, D, DF);
  transpose_f32_bf16<<<dim3(D / 32, DF / 32), blk, 0, stream>>>(Wff2, wff2t, DF, D);

  // ---- stage 1: causal self-attention + add&norm ----
  // Q|K projection: merged WQ^T||WK^T view (contiguous), C = QKb [8192][2048]
  gemm256<EPI_BF16, MODE_FULL, 256, 256><<<dim3(2 * D / 256, BS / 256, 1), blk512, 0, stream>>>(
      ybf, wq1t, QKb, nullptr, nullptr, nullptr, 0, D, D, D, 2 * D, 0, 0, 0);
  // V^T: Vt[d][s] = sum_k WvT[d][k] * X[s][k]  -> C [1024][8192]
  gemm256<EPI_BF16, MODE_FULL, 128, 256><<<dim3((unsigned)(BS / 256), D / 128, 1), blk512, 0, stream>>>(
      wv1t, ybf, Vtb, nullptr, nullptr, nullptr, 0, D, D, D, (int)BS, 0, 0, 0);
  // causal scores: lower-triangle 256x128 tiles (72/batch -> 288 blocks)
  gemm256<EPI_BF16_SCALE, MODE_TRI, 256, 128><<<dim3(72, 1, Bn), blk512, 0, stream>>>(
      QKb, QKb + D, SPb, nullptr, nullptr, nullptr, 0, D, 2 * D, 2 * D, S, SD2, SD2, SS);
  softmax_bf16<<<dim3((unsigned)(Bn * S)), blk, 0, stream>>>(SPb, 1);
  // PV: K-loop clamped to diagonal (P == 0 above it)
  gemm256<EPI_F32, MODE_CAUSAL_K, 256, 128><<<dim3(D / 128, S / 256, Bn), blk512, 0, stream>>>(
      SPb, Vtb, attnF, nullptr, nullptr, nullptr, 0, S, S, (int)BS, D, SS, S, SD);
  ln_residual<0><<<dim3((unsigned)BS), blk, 0, stream>>>(y_in, attnF, g1, be1, nullptr, y1b);

  // ---- stage 2: cross-attention + add&norm ----
  // fused Q2|K2 projection: ni<8 -> Q (y1b x wq2t), ni>=8 -> K (zbf x wk2t)
  gemm256<EPI_BF16, MODE_FULL, 256, 128><<<dim3(2 * D / 128, BS / 256, 1), blk512, 0, stream>>>(
      y1b, wq2t, QKb, nullptr, zbf, wk2t, 8, D, D, D, 2 * D, 0, 0, 0);
  gemm256<EPI_BF16, MODE_FULL, 128, 256><<<dim3((unsigned)(BS / 256), D / 128, 1), blk512, 0, stream>>>(
      wv2t, zbf, Vtb, nullptr, nullptr, nullptr, 0, D, D, D, (int)BS, 0, 0, 0);
  gemm256<EPI_BF16_SCALE, MODE_FULL, 256, 256><<<dim3(S / 256, S / 256, Bn), blk512, 0, stream>>>(
      QKb, QKb + D, SPb, nullptr, nullptr, nullptr, 0, D, 2 * D, 2 * D, S, SD2, SD2, SS);
  softmax_bf16<<<dim3((unsigned)(Bn * S)), blk, 0, stream>>>(SPb, 0);
  gemm256<EPI_F32, MODE_FULL, 256, 128><<<dim3(D / 128, S / 256, Bn), blk512, 0, stream>>>(
      SPb, Vtb, attnF, nullptr, nullptr, nullptr, 0, S, S, (int)BS, D, SS, S, SD);
  ln_residual<1><<<dim3((unsigned)BS), blk, 0, stream>>>(y1b, attnF, g2, be2, nullptr, y2b);

  // ---- stage 3: FFN + add&norm ----
  gemm256<EPI_BIAS_RELU_BF16, MODE_FULL, 256, 256><<<dim3(DF / 256, BS / 256, 1), blk512, 0, stream>>>(
      y2b, wff1t, Hb, bff1, nullptr, nullptr, 0, D, D, D, DF, 0, 0, 0);
  gemm256<EPI_BIAS_F32, MODE_FULL, 256, 128><<<dim3(D / 128, BS / 256, 1), blk512, 0, stream>>>(
      Hb, wff2t, Fb, bff2, nullptr, nullptr, 0, DF, DF, DF, D, 0, 0, 0);
  ln_residual<1><<<dim3((unsigned)BS), blk, 0, stream>>>(y2b, Fb, g3, be3, (float*)d_out, nullptr);
}